// Round 7
// baseline (485.964 us; speedup 1.0000x reference)
//
#include <hip/hip_runtime.h>

// ---------------------------------------------------------------------------
// net_lstm: graph-constructor (topk-20 sparse adj) + per-node LSTM (bf16 MFMA)
//           + mixprop x2 (sparse gather + uniform-weight proj) + layernorm.
// Only layer j=2 of the 3 layers affects the output (reference overwrites h).
// ALL tensors are FLOAT32 on device. LSTM matmul in bf16 MFMA, rest fp32.
// All reciprocals via v_rcp_f32 (~1ulp; tolerance is 2% of absmax).
// ---------------------------------------------------------------------------

typedef unsigned short u16;
typedef __attribute__((ext_vector_type(8))) short bf16x8;   // 8 bf16 = 4 VGPR (MFMA A/B frag)
typedef __attribute__((ext_vector_type(4))) float fx4;      // MFMA C/D frag

#define NB 64          // batch
#define NNODE 1000
#define TT 12
#define FF 32
#define HH 64
#define DD 40
#define TOPK_ 20
#define EPR 21         // entries per adjacency row (topk + diagonal)

__device__ __forceinline__ float rcp_f(float x) { return __builtin_amdgcn_rcpf(x); }
__device__ __forceinline__ float tanh_f(float x) {          // NaN-safe: e>=0 always
  return fmaf(-2.0f, rcp_f(__expf(2.0f * x) + 1.0f), 1.0f);
}
__device__ __forceinline__ unsigned int cvt_pk(float lo, float hi) {
  unsigned int r;                                           // r = [bf16(hi)|bf16(lo)]
  asm("v_cvt_pk_bf16_f32 %0, %1, %2" : "=v"(r) : "v"(lo), "v"(hi));
  return r;
}
__device__ __forceinline__ bf16x8 cvt8(const float* p) {    // 8 fp32 -> bf16x8 (4 cvt_pk)
  union { unsigned int u[4]; bf16x8 v; } r;
  #pragma unroll
  for (int e = 0; e < 4; e++) r.u[e] = cvt_pk(p[2 * e], p[2 * e + 1]);
  return r.v;
}
__device__ __forceinline__ bf16x8 cvt8v(float4 a, float4 b) {
  union { unsigned int u[4]; bf16x8 v; } r;
  r.u[0] = cvt_pk(a.x, a.y); r.u[1] = cvt_pk(a.z, a.w);
  r.u[2] = cvt_pk(b.x, b.y); r.u[3] = cvt_pk(b.z, b.w);
  return r.v;
}

// ---------------- K1: m1/m2 = tanh(3*(emb @ w^T + b)) -----------------------
__global__ void k_m1m2(const float* __restrict__ emb1, const float* __restrict__ emb2,
                       const float* __restrict__ w1, const float* __restrict__ b1,
                       const float* __restrict__ w2, const float* __restrict__ b2,
                       float* __restrict__ m1, float* __restrict__ m2) {
  int id = blockIdx.x * 256 + threadIdx.x;
  if (id >= 2 * NNODE * DD) return;
  int sel = id / (NNODE * DD);
  int r = id % (NNODE * DD);
  int i = r / DD, o = r % DD;
  const float* emb = sel ? emb2 : emb1;
  const float* w = sel ? w2 : w1;
  const float* bb = sel ? b2 : b1;
  float s = bb[o];
  for (int k = 0; k < DD; k++) s = fmaf(emb[i * DD + k], w[o * DD + k], s);
  (sel ? m2 : m1)[r] = tanh_f(3.0f * s);
}

// ---------------- K2: adjacency row + top-20 + normalize --------------------
// Row v of a = relu(tanh(3*(m1 v . m2 w - m2 v . m1 w))); diag is exactly 0, so
// adj = a*mask + I has diag exactly 1. Sparse output: packed int2 {idx, val}.
// Selection: wave 0 only, scores held in 16 regs/lane, 20 passes with
// __shfl_xor butterfly (all lanes learn winner) — ZERO barriers, all reg
// indices static (rule #20). Tie-break: value desc, index asc (= lax.top_k).
__global__ void k_adj(const float* __restrict__ m1, const float* __restrict__ m2,
                      int2* __restrict__ pae) {
  int v = blockIdx.x, tid = threadIdx.x;
  __shared__ float arow[NNODE];
  __shared__ float m1v[DD], m2v[DD];
  if (tid < DD) { m1v[tid] = m1[v * DD + tid]; m2v[tid] = m2[v * DD + tid]; }
  __syncthreads();
  for (int w = tid; w < NNODE; w += 256) {
    float d1 = 0.f, d2 = 0.f;
    #pragma unroll 8
    for (int k = 0; k < DD; k++) {
      d1 = fmaf(m1v[k], m2[w * DD + k], d1);
      d2 = fmaf(m2v[k], m1[w * DD + k], d2);
    }
    arow[w] = fmaxf(tanh_f(3.0f * (d1 - d2)), 0.0f);
  }
  __syncthreads();
  if (tid >= 64) return;                 // selection: wave 0 only
  int l = tid;
  float rv[16];
  #pragma unroll
  for (int q = 0; q < 16; q++) {
    int idx = q * 64 + l;
    rv[q] = (idx < NNODE) ? arow[idx] : -2.f;
  }
  float rs = 1.f;                        // diagonal contributes 1
  float myv = 0.f; int myi = 0;          // lane l carries selected entry (l-1)
  #pragma unroll
  for (int sel = 0; sel < TOPK_; sel++) {
    float bv = rv[0]; int bi = l;
    #pragma unroll
    for (int q = 1; q < 16; q++) {
      int idx = q * 64 + l;
      if (rv[q] > bv) { bv = rv[q]; bi = idx; }   // ascending q => lowest idx on tie
    }
    #pragma unroll
    for (int off = 1; off < 64; off <<= 1) {
      float ov = __shfl_xor(bv, off); int oi = __shfl_xor(bi, off);
      if (ov > bv || (ov == bv && oi < bi)) { bv = ov; bi = oi; }
    }
    rs += bv;
    if (l == sel + 1) { myv = bv; myi = bi; }
    #pragma unroll
    for (int q = 0; q < 16; q++)
      if (q * 64 + l == bi) rv[q] = -2.f;         // invalidate winner
  }
  float inv = rcp_f(rs);
  if (l == 0)          pae[v * EPR] = make_int2(v, __float_as_int(inv));
  else if (l <= TOPK_) pae[v * EPR + l] = make_int2(myi, __float_as_int(myv * inv));
}

// ---------------- K3: LSTM over 12 steps, bf16 MFMA -------------------------
// Block = 256 thr = 4 waves; wave owns 16 sequences, computes all 256 gate cols.
// mfma_f32_16x16x32_bf16: A frag row=lane&15, k=(lane>>4)*8+e (consecutive 8);
// B frag col=lane&15 same k; D col=lane&15, row=(lane>>4)*4+reg  [m89/m92].
// Column remap: logical col L = nt*16 + c holds gate g=nt>>2, hidden
// j = c*4 + (nt&3).  => thread (c=arow) at acc[njt][i] owns (seq kg*4+i,
// j = arow*4+njt): i/f/g/o in SAME lane, consecutive j -> b64 LDS shuttle +
// float4 final store. x is software-prefetched one step ahead (load latency
// hides under barrier+MFMA+gates). Gate math in common-denominator form:
// 7 trans ops/unit (5 exp + 2 rcp) instead of 10. acc[] statically indexed
// (rule #20). Opaque-zero zo keeps whf loads loop-variant (no LICM spill).
__global__ __launch_bounds__(256, 4)
void k_lstm(const float* __restrict__ x, const float* __restrict__ Wih,
            const float* __restrict__ Whh, const float* __restrict__ bih,
            const float* __restrict__ bhh, float* __restrict__ hout) {
  __shared__ __align__(16) u16 whf[2 * 16 * 64 * 8];  // Whh frags [ks][nt][lane][8] (32 KB)
  __shared__ __align__(16) u16 hsh[4][16][64];        // per-wave h shuttle (8 KB)
  int tid = threadIdx.x, wave = tid >> 6, lane = tid & 63;
  int arow = lane & 15, kg = lane >> 4;

  // stage Whh frags: frag(ks,nt,l,e) = Whh[row=(nt>>2)*64+(l&15)*4+(nt&3)][ks*32+(l>>4)*8+e]
  for (int cc = tid; cc < 2 * 16 * 64; cc += 256) {
    int l = cc & 63, t16 = cc >> 6, ks = t16 >> 4, nt = t16 & 15;
    int row = (nt >> 2) * 64 + (l & 15) * 4 + (nt & 3);
    *(bf16x8*)&whf[cc * 8] = cvt8(Whh + row * 64 + ks * 32 + (l >> 4) * 8);
  }
  __syncthreads();

  bf16x8 wi[16];                                      // Wih fragments in registers
  float biasv[16];
  #pragma unroll
  for (int nt = 0; nt < 16; nt++) {
    int row = (nt >> 2) * 64 + arow * 4 + (nt & 3);
    wi[nt] = cvt8(Wih + row * 32 + kg * 8);
    biasv[nt] = bih[row] + bhh[row];
  }

  int seq_base = blockIdx.x * 64 + wave * 16;
  const float* xb = x + (size_t)(seq_base + arow) * (TT * FF) + kg * 8;
  float cst[16];
  #pragma unroll
  for (int q = 0; q < 16; q++) cst[q] = 0.f;
  fx4 acc[16];

  float4 xf0 = *(const float4*)(xb);                  // prefetch t=0
  float4 xf1 = *(const float4*)(xb + 4);

  #pragma unroll 1
  for (int t = 0; t < TT; t++) {
    unsigned int zo = 0;                 // opaque zero, renewed each iteration:
    asm volatile("" : "+v"(zo));         // whf load addrs loop-variant => no LICM
    bf16x8 xa = cvt8v(xf0, xf1);         // consume prefetched x(t)
    if (t < TT - 1) {                    // issue x(t+1) load; latency hides
      xf0 = *(const float4*)(xb + (t + 1) * FF);      // under barrier+MFMA+gates
      xf1 = *(const float4*)(xb + (t + 1) * FF + 4);
    }
    #pragma unroll
    for (int nt = 0; nt < 16; nt++)
      acc[nt] = (fx4){biasv[nt], biasv[nt], biasv[nt], biasv[nt]};
    #pragma unroll
    for (int nt = 0; nt < 16; nt++)
      acc[nt] = __builtin_amdgcn_mfma_f32_16x16x32_bf16(xa, wi[nt], acc[nt], 0, 0, 0);
    if (t > 0) {
      __syncthreads();                   // h shuttle: write(t-1) -> read(t)
      bf16x8 ha0 = *(const bf16x8*)&hsh[wave][arow][kg * 8];
      bf16x8 ha1 = *(const bf16x8*)&hsh[wave][arow][32 + kg * 8];
      #pragma unroll
      for (int nt = 0; nt < 16; nt++) {
        bf16x8 wb = *(const bf16x8*)&whf[(nt * 64 + lane) * 8 + zo];
        acc[nt] = __builtin_amdgcn_mfma_f32_16x16x32_bf16(ha0, wb, acc[nt], 0, 0, 0);
      }
      #pragma unroll
      for (int nt = 0; nt < 16; nt++) {
        bf16x8 wb = *(const bf16x8*)&whf[((16 + nt) * 64 + lane) * 8 + zo];
        acc[nt] = __builtin_amdgcn_mfma_f32_16x16x32_bf16(ha1, wb, acc[nt], 0, 0, 0);
      }
    }
    // gates: seq = kg*4+i, hidden j = arow*4+njt. Common-denominator forms:
    // c = (cprev*B + (eg-1)*A) / (A*B),  A=1+e^-f, B=(1+e^-i)(e^2g+1)
    // h = (ec-1) / ((ec+1)(1+e^-o)),     ec=e^2c      [7 trans vs 10]
    #pragma unroll
    for (int i = 0; i < 4; i++) {
      float hq[4];
      #pragma unroll
      for (int njt = 0; njt < 4; njt++) {
        float iv = acc[njt][i], fv = acc[njt + 4][i];
        float gv = acc[njt + 8][i], ov = acc[njt + 12][i];
        float cpv = cst[i * 4 + njt];
        float ei = __expf(-iv), ef = __expf(-fv);
        float eg = __expf(2.0f * gv), eo = __expf(-ov);
        float A = 1.0f + ef;
        float B = (1.0f + ei) * (eg + 1.0f);
        float c = fmaf(cpv, B, (eg - 1.0f) * A) * rcp_f(A * B);
        cst[i * 4 + njt] = c;
        float ec = __expf(2.0f * c);
        hq[njt] = (ec - 1.0f) * rcp_f((ec + 1.0f) * (1.0f + eo));
      }
      if (t < TT - 1) {
        unsigned int p0 = cvt_pk(hq[0], hq[1]);
        unsigned int p1 = cvt_pk(hq[2], hq[3]);
        *(uint2*)&hsh[wave][kg * 4 + i][arow * 4] = make_uint2(p0, p1);
      } else {
        *(float4*)&hout[(size_t)(seq_base + kg * 4 + i) * HH + arow * 4] =
            (float4){hq[0], hq[1], hq[2], hq[3]};
      }
    }
  }
}

// ---------------- K_prep: layer-2 weights transposed into ws ----------------
// wt layout (all fp32): [0..767] lin_w^T [k][s]; [768..779] lin_b;
// [784..1935] mp1_w^T [c][o=32]; [1936..1967] mp1_b;
// [1968..5807] mp2_w^T [c][o=40]; [5808..5847] mp2_b.
__global__ void k_prep(const float* __restrict__ lw, const float* __restrict__ lb,
                       const float* __restrict__ w1, const float* __restrict__ b1,
                       const float* __restrict__ w2, const float* __restrict__ b2,
                       float* __restrict__ wt) {
  int tid = threadIdx.x;
  for (int i = tid; i < 768; i += 256) { int k = i / 12, s = i % 12; wt[i] = lw[s * 64 + k]; }
  if (tid < 12) wt[768 + tid] = lb[tid];
  for (int i = tid; i < 1152; i += 256) { int c = i / 32, o = i % 32; wt[784 + i] = w1[o * 36 + c]; }
  if (tid < 32) wt[1936 + tid] = b1[tid];
  for (int i = tid; i < 3840; i += 256) { int c = i / 40, o = i % 40; wt[1968 + i] = w2[o * 96 + c]; }
  if (tid < 40) wt[5808 + tid] = b2[tid];
}

// ---------------- K4: hj[b][s][n] = h[b*1000+n] . lin_w2[s] + lin_b2[s] -----
__global__ void k_hj(const float* __restrict__ h, const float* __restrict__ wt,
                     float* __restrict__ hj) {
  int id = blockIdx.x * 256 + threadIdx.x;     // (b,n), 64000 total
  int b = id / NNODE, n = id % NNODE;
  const float* hr = h + (size_t)id * HH;
  float hv[HH];
  #pragma unroll
  for (int k = 0; k < HH; k += 4) {
    float4 t4 = *(const float4*)(hr + k);
    hv[k] = t4.x; hv[k + 1] = t4.y; hv[k + 2] = t4.z; hv[k + 3] = t4.w;
  }
  float acc[12];
  #pragma unroll
  for (int s = 0; s < 12; s++) acc[s] = wt[768 + s];
  for (int k = 0; k < HH; k++) {
    float hvk = hv[k];
    #pragma unroll
    for (int s = 0; s < 12; s++) acc[s] = fmaf(hvk, wt[k * 12 + s], acc[s]);  // uniform -> SGPR
  }
  #pragma unroll
  for (int s = 0; s < 12; s++) hj[(size_t)(b * 12 + s) * NNODE + n] = acc[s];
}

// ---------------- K5/K7: mixprop propagation (gdep=2) -----------------------
// block = b*C + c. ho[b][d*C+c][:] for d=0,1,2 with h_{k+1}=0.05*x0+0.95*A h_k.
__global__ void k_prop(const float* __restrict__ hin, const int2* __restrict__ pae,
                       float* __restrict__ ho, int C) {
  int blk = blockIdx.x;
  int b = blk / C, c = blk % C;
  __shared__ float r0[NNODE], r1[NNODE];
  int tid = threadIdx.x;
  const float* src = hin + (size_t)(b * C + c) * NNODE;
  float* dst = ho + (size_t)(b * 3 * C) * NNODE;
  for (int n = tid; n < NNODE; n += 256) {
    float vv = src[n]; r0[n] = vv; dst[(size_t)c * NNODE + n] = vv;
  }
  __syncthreads();
  for (int n = tid; n < NNODE; n += 256) {
    const int2* pa = pae + n * EPR;
    float s = 0.f;
    #pragma unroll
    for (int e = 0; e < EPR; e++) { int2 p = pa[e]; s = fmaf(__int_as_float(p.y), r0[p.x], s); }
    float h1 = 0.05f * r0[n] + 0.95f * s;
    r1[n] = h1; dst[(size_t)(C + c) * NNODE + n] = h1;
  }
  __syncthreads();
  for (int n = tid; n < NNODE; n += 256) {
    const int2* pa = pae + n * EPR;
    float s = 0.f;
    #pragma unroll
    for (int e = 0; e < EPR; e++) { int2 p = pa[e]; s = fmaf(__int_as_float(p.y), r1[p.x], s); }
    dst[(size_t)(2 * C + c) * NNODE + n] = 0.05f * r0[n] + 0.95f * s;
  }
}

// ---------------- K6/K8: channel projection (uniform weights -> SGPR) -------
template <int CIN, int COUT>
__global__ void k_proj(const float* __restrict__ hin, const float* __restrict__ wt,
                       const float* __restrict__ bb, float* __restrict__ out, int relu) {
  int id = blockIdx.x * 256 + threadIdx.x;   // (b,n)
  int b = id / NNODE, n = id % NNODE;
  float acc[COUT];
  #pragma unroll
  for (int o = 0; o < COUT; o++) acc[o] = bb[o];
  for (int c = 0; c < CIN; c++) {
    float hv = hin[(size_t)(b * CIN + c) * NNODE + n];
    #pragma unroll
    for (int o = 0; o < COUT; o++) acc[o] = fmaf(hv, wt[c * COUT + o], acc[o]);
  }
  #pragma unroll
  for (int o = 0; o < COUT; o++) {
    float vv = acc[o];
    if (relu) vv = fmaxf(vv, 0.f);
    out[(size_t)(b * COUT + o) * NNODE + n] = vv;
  }
}

// ---------------- K9: layernorm stats over (40,1000) per batch --------------
__global__ void k_lnstat(const float* __restrict__ hj2, float* __restrict__ stat) {
  int b = blockIdx.x, tid = threadIdx.x, lane = tid & 63, wave = tid >> 6;
  const float* p = hj2 + (size_t)b * DD * NNODE;
  float s = 0.f, q = 0.f;
  for (int i = tid; i < DD * NNODE; i += 256) { float vv = p[i]; s += vv; q = fmaf(vv, vv, q); }
  for (int off = 32; off; off >>= 1) { s += __shfl_down(s, off); q += __shfl_down(q, off); }
  __shared__ float ss[4], sq[4];
  if (lane == 0) { ss[wave] = s; sq[wave] = q; }
  __syncthreads();
  if (tid == 0) {
    const float invN = 1.0f / (float)(DD * NNODE);
    float S = ss[0] + ss[1] + ss[2] + ss[3];
    float Q = sq[0] + sq[1] + sq[2] + sq[3];
    float mu = S * invN;
    float var = Q * invN - mu * mu;
    stat[2 * b] = mu; stat[2 * b + 1] = __builtin_amdgcn_rsqf(var + 1e-5f);
  }
}

// ---------------- K10: apply LN + transpose + fp32 out ----------------------
__global__ void k_lnapply(const float* __restrict__ hj2, const float* __restrict__ stat,
                          const float* __restrict__ gamma, const float* __restrict__ beta,
                          float* __restrict__ out) {
  int id = blockIdx.x * 256 + threadIdx.x;   // (b,n)
  int b = id / NNODE, n = id % NNODE;
  float mu = stat[2 * b], rstd = stat[2 * b + 1];
  size_t obase = (size_t)b * (NNODE * DD) + (size_t)n * DD;
  #pragma unroll
  for (int d0 = 0; d0 < DD / 4; d0++) {
    float tt[4];
    #pragma unroll
    for (int q = 0; q < 4; q++) {
      int d = d0 * 4 + q;
      float h0 = hj2[(size_t)(b * DD + d) * NNODE + n];
      tt[q] = (h0 - mu) * rstd * gamma[d * NNODE + n] + beta[d * NNODE + n];
    }
    *(float4*)(out + obase + d0 * 4) = (float4){tt[0], tt[1], tt[2], tt[3]};
  }
}

// ---------------- workspace layout (fp32 words) -----------------------------
// 0        m1(40000) | 40000 m2(40000) | 80000 pae(21000 int2 = 42000 words)
// 122000   h_lstm(4.096M)  [reused by ho2 after K4]
// 4218000  hj(768000) | 4986000 ho1(2.304M) | 7290000 o1(2.048M)
// 122000   ho2(6.144M)  [overlaps dead h_lstm/hj/ho1; ends 6266000 < 7290000]
// 9338000  hj2(2.56M) | 11898000 stat(128) | 11898128 wt(5848)   total ~47.6 MB
#define OFF_M1   0
#define OFF_M2   40000
#define OFF_PAE  80000
#define OFF_H    122000
#define OFF_HJ   4218000
#define OFF_HO1  4986000
#define OFF_O1   7290000
#define OFF_HO2  122000
#define OFF_HJ2  9338000
#define OFF_STAT 11898000
#define OFF_WT   11898128

extern "C" void kernel_launch(void* const* d_in, const int* in_sizes, int n_in,
                              void* d_out, int out_size, void* d_ws, size_t ws_size,
                              hipStream_t stream) {
  (void)in_sizes; (void)n_in; (void)out_size; (void)ws_size;
  const float* x     = (const float*)d_in[0];
  const float* emb1  = (const float*)d_in[1];
  const float* emb2  = (const float*)d_in[2];
  const float* l1w   = (const float*)d_in[3];
  const float* l1b   = (const float*)d_in[4];
  const float* l2w   = (const float*)d_in[5];
  const float* l2b   = (const float*)d_in[6];
  const float* Wih   = (const float*)d_in[7];
  const float* Whh   = (const float*)d_in[8];
  const float* bih   = (const float*)d_in[9];
  const float* bhh   = (const float*)d_in[10];
  const float* lin_w = (const float*)d_in[11];
  const float* lin_b = (const float*)d_in[12];
  const float* mp1w  = (const float*)d_in[13];
  const float* mp1b  = (const float*)d_in[14];
  const float* mp2w  = (const float*)d_in[15];
  const float* mp2b  = (const float*)d_in[16];
  const float* gamma = (const float*)d_in[17];
  const float* beta  = (const float*)d_in[18];

  float* ws   = (float*)d_ws;
  float* m1   = ws + OFF_M1;
  float* m2   = ws + OFF_M2;
  int2*  pae  = (int2*)(ws + OFF_PAE);
  float* hl   = ws + OFF_H;
  float* hj   = ws + OFF_HJ;
  float* ho1  = ws + OFF_HO1;
  float* o1   = ws + OFF_O1;
  float* ho2  = ws + OFF_HO2;
  float* hj2  = ws + OFF_HJ2;
  float* stat = ws + OFF_STAT;
  float* wt   = ws + OFF_WT;

  k_m1m2<<<dim3(313), dim3(256), 0, stream>>>(emb1, emb2, l1w, l1b, l2w, l2b, m1, m2);
  k_prep<<<dim3(1), dim3(256), 0, stream>>>(lin_w + 1536, lin_b + 24, mp1w + 2304, mp1b + 64,
                                            mp2w + 7680, mp2b + 80, wt);
  k_adj<<<dim3(NNODE), dim3(256), 0, stream>>>(m1, m2, pae);
  k_lstm<<<dim3(1000), dim3(256), 0, stream>>>(x, Wih, Whh, bih, bhh, hl);
  k_hj<<<dim3(250), dim3(256), 0, stream>>>(hl, wt, hj);
  k_prop<<<dim3(64 * 12), dim3(256), 0, stream>>>(hj, pae, ho1, 12);
  k_proj<36, 32><<<dim3(250), dim3(256), 0, stream>>>(ho1, wt + 784, wt + 1936, o1, 1);
  k_prop<<<dim3(64 * 32), dim3(256), 0, stream>>>(o1, pae, ho2, 32);
  k_proj<96, 40><<<dim3(250), dim3(256), 0, stream>>>(ho2, wt + 1968, wt + 5808, hj2, 0);
  k_lnstat<<<dim3(NB), dim3(256), 0, stream>>>(hj2, stat);
  k_lnapply<<<dim3(250), dim3(256), 0, stream>>>(hj2, stat, gamma + 80000, beta + 80000,
                                                 (float*)d_out);
}

// Round 8
// 316.304 us; speedup vs baseline: 1.5364x; 1.5364x over previous
//
#include <hip/hip_runtime.h>

// ---------------------------------------------------------------------------
// net_lstm: graph-constructor (topk-20 sparse adj) + per-node LSTM (bf16 MFMA)
//           + mixprop x2 (sparse gather + uniform-weight proj) + layernorm.
// Only layer j=2 of the 3 layers affects the output (reference overwrites h).
// ALL tensors are FLOAT32 on device. LSTM matmul in bf16 MFMA, rest fp32.
// NOTE: k_lstm is REGISTER-BOUND by design (weights in regs + 64 AGPR acc).
// __launch_bounds__ min-waves MUST stay at 2: (256,4) caps regs at 128 incl
// AGPRs -> 850 MB scratch spill, 2.5x slower (round-7 regression, measured).
// ---------------------------------------------------------------------------

typedef unsigned short u16;
typedef __attribute__((ext_vector_type(8))) short bf16x8;   // 8 bf16 = 4 VGPR (MFMA A/B frag)
typedef __attribute__((ext_vector_type(4))) float fx4;      // MFMA C/D frag

#define NB 64          // batch
#define NNODE 1000
#define TT 12
#define FF 32
#define HH 64
#define DD 40
#define TOPK_ 20
#define EPR 21         // entries per adjacency row (topk + diagonal)

__device__ __forceinline__ float rcp_f(float x) { return __builtin_amdgcn_rcpf(x); }
__device__ __forceinline__ float tanh_f(float x) {          // NaN-safe: e>=0 always
  return fmaf(-2.0f, rcp_f(__expf(2.0f * x) + 1.0f), 1.0f);
}
__device__ __forceinline__ unsigned int cvt_pk(float lo, float hi) {
  unsigned int r;                                           // r = [bf16(hi)|bf16(lo)]
  asm("v_cvt_pk_bf16_f32 %0, %1, %2" : "=v"(r) : "v"(lo), "v"(hi));
  return r;
}
__device__ __forceinline__ bf16x8 cvt8(const float* p) {    // 8 fp32 -> bf16x8 (4 cvt_pk)
  union { unsigned int u[4]; bf16x8 v; } r;
  #pragma unroll
  for (int e = 0; e < 4; e++) r.u[e] = cvt_pk(p[2 * e], p[2 * e + 1]);
  return r.v;
}
__device__ __forceinline__ bf16x8 cvt8v(float4 a, float4 b) {
  union { unsigned int u[4]; bf16x8 v; } r;
  r.u[0] = cvt_pk(a.x, a.y); r.u[1] = cvt_pk(a.z, a.w);
  r.u[2] = cvt_pk(b.x, b.y); r.u[3] = cvt_pk(b.z, b.w);
  return r.v;
}

// ---------------- K1: m1/m2 = tanh(3*(emb @ w^T + b)) -----------------------
__global__ void k_m1m2(const float* __restrict__ emb1, const float* __restrict__ emb2,
                       const float* __restrict__ w1, const float* __restrict__ b1,
                       const float* __restrict__ w2, const float* __restrict__ b2,
                       float* __restrict__ m1, float* __restrict__ m2) {
  int id = blockIdx.x * 256 + threadIdx.x;
  if (id >= 2 * NNODE * DD) return;
  int sel = id / (NNODE * DD);
  int r = id % (NNODE * DD);
  int i = r / DD, o = r % DD;
  const float* emb = sel ? emb2 : emb1;
  const float* w = sel ? w2 : w1;
  const float* bb = sel ? b2 : b1;
  float s = bb[o];
  for (int k = 0; k < DD; k++) s = fmaf(emb[i * DD + k], w[o * DD + k], s);
  (sel ? m2 : m1)[r] = tanh_f(3.0f * s);
}

// ---------------- K2: adjacency row + top-20 + normalize --------------------
// Row v of a = relu(tanh(3*(m1 v . m2 w - m2 v . m1 w))); diag is exactly 0, so
// adj = a*mask + I has diag exactly 1. Sparse output: packed int2 {idx, val}.
// Selection: wave 0 only, scores held in 16 regs/lane, 20 passes with
// __shfl_xor butterfly (all lanes learn winner) — ZERO barriers, all reg
// indices static (rule #20). Tie-break: value desc, index asc (= lax.top_k).
__global__ void k_adj(const float* __restrict__ m1, const float* __restrict__ m2,
                      int2* __restrict__ pae) {
  int v = blockIdx.x, tid = threadIdx.x;
  __shared__ float arow[NNODE];
  __shared__ float m1v[DD], m2v[DD];
  if (tid < DD) { m1v[tid] = m1[v * DD + tid]; m2v[tid] = m2[v * DD + tid]; }
  __syncthreads();
  for (int w = tid; w < NNODE; w += 256) {
    float d1 = 0.f, d2 = 0.f;
    #pragma unroll 8
    for (int k = 0; k < DD; k++) {
      d1 = fmaf(m1v[k], m2[w * DD + k], d1);
      d2 = fmaf(m2v[k], m1[w * DD + k], d2);
    }
    arow[w] = fmaxf(tanh_f(3.0f * (d1 - d2)), 0.0f);
  }
  __syncthreads();
  if (tid >= 64) return;                 // selection: wave 0 only
  int l = tid;
  float rv[16];
  #pragma unroll
  for (int q = 0; q < 16; q++) {
    int idx = q * 64 + l;
    rv[q] = (idx < NNODE) ? arow[idx] : -2.f;
  }
  float rs = 1.f;                        // diagonal contributes 1
  float myv = 0.f; int myi = 0;          // lane l carries selected entry (l-1)
  #pragma unroll
  for (int sel = 0; sel < TOPK_; sel++) {
    float bv = rv[0]; int bi = l;
    #pragma unroll
    for (int q = 1; q < 16; q++) {
      int idx = q * 64 + l;
      if (rv[q] > bv) { bv = rv[q]; bi = idx; }   // ascending q => lowest idx on tie
    }
    #pragma unroll
    for (int off = 1; off < 64; off <<= 1) {
      float ov = __shfl_xor(bv, off); int oi = __shfl_xor(bi, off);
      if (ov > bv || (ov == bv && oi < bi)) { bv = ov; bi = oi; }
    }
    rs += bv;
    if (l == sel + 1) { myv = bv; myi = bi; }
    #pragma unroll
    for (int q = 0; q < 16; q++)
      if (q * 64 + l == bi) rv[q] = -2.f;         // invalidate winner
  }
  float inv = rcp_f(rs);
  if (l == 0)          pae[v * EPR] = make_int2(v, __float_as_int(inv));
  else if (l <= TOPK_) pae[v * EPR + l] = make_int2(myi, __float_as_int(myv * inv));
}

// ---------------- K3: LSTM over 12 steps, bf16 MFMA -------------------------
// Block = 256 thr = 4 waves; wave owns 16 sequences, computes all 256 gate cols.
// mfma_f32_16x16x32_bf16: A frag row=lane&15, k=(lane>>4)*8+e (consecutive 8);
// B frag col=lane&15 same k; D col=lane&15, row=(lane>>4)*4+reg  [m89/m92].
// Column remap: logical col L = nt*16 + c holds gate g=nt>>2, hidden
// j = c*4 + (nt&3).  => thread (c=arow) at acc[njt][i] owns (seq kg*4+i,
// j = arow*4+njt): i/f/g/o in SAME lane, consecutive j -> b64 LDS shuttle +
// float4 final store. x is software-prefetched one step ahead (load latency
// hides under barrier+MFMA+gates). Gate math in common-denominator form:
// 7 trans ops/unit (5 exp + 2 rcp) instead of 10. acc[] statically indexed
// (rule #20). Opaque-zero zo keeps whf loads loop-variant (no LICM spill).
__global__ __launch_bounds__(256, 2)
void k_lstm(const float* __restrict__ x, const float* __restrict__ Wih,
            const float* __restrict__ Whh, const float* __restrict__ bih,
            const float* __restrict__ bhh, float* __restrict__ hout) {
  __shared__ __align__(16) u16 whf[2 * 16 * 64 * 8];  // Whh frags [ks][nt][lane][8] (32 KB)
  __shared__ __align__(16) u16 hsh[4][16][64];        // per-wave h shuttle (8 KB)
  int tid = threadIdx.x, wave = tid >> 6, lane = tid & 63;
  int arow = lane & 15, kg = lane >> 4;

  // stage Whh frags: frag(ks,nt,l,e) = Whh[row=(nt>>2)*64+(l&15)*4+(nt&3)][ks*32+(l>>4)*8+e]
  for (int cc = tid; cc < 2 * 16 * 64; cc += 256) {
    int l = cc & 63, t16 = cc >> 6, ks = t16 >> 4, nt = t16 & 15;
    int row = (nt >> 2) * 64 + (l & 15) * 4 + (nt & 3);
    *(bf16x8*)&whf[cc * 8] = cvt8(Whh + row * 64 + ks * 32 + (l >> 4) * 8);
  }
  __syncthreads();

  bf16x8 wi[16];                                      // Wih fragments in registers
  float biasv[16];
  #pragma unroll
  for (int nt = 0; nt < 16; nt++) {
    int row = (nt >> 2) * 64 + arow * 4 + (nt & 3);
    wi[nt] = cvt8(Wih + row * 32 + kg * 8);
    biasv[nt] = bih[row] + bhh[row];
  }

  int seq_base = blockIdx.x * 64 + wave * 16;
  const float* xb = x + (size_t)(seq_base + arow) * (TT * FF) + kg * 8;
  float cst[16];
  #pragma unroll
  for (int q = 0; q < 16; q++) cst[q] = 0.f;
  fx4 acc[16];

  float4 xf0 = *(const float4*)(xb);                  // prefetch t=0
  float4 xf1 = *(const float4*)(xb + 4);

  #pragma unroll 1
  for (int t = 0; t < TT; t++) {
    unsigned int zo = 0;                 // opaque zero, renewed each iteration:
    asm volatile("" : "+v"(zo));         // whf load addrs loop-variant => no LICM
    bf16x8 xa = cvt8v(xf0, xf1);         // consume prefetched x(t)
    if (t < TT - 1) {                    // issue x(t+1) load; latency hides
      xf0 = *(const float4*)(xb + (t + 1) * FF);      // under barrier+MFMA+gates
      xf1 = *(const float4*)(xb + (t + 1) * FF + 4);
    }
    #pragma unroll
    for (int nt = 0; nt < 16; nt++)
      acc[nt] = (fx4){biasv[nt], biasv[nt], biasv[nt], biasv[nt]};
    #pragma unroll
    for (int nt = 0; nt < 16; nt++)
      acc[nt] = __builtin_amdgcn_mfma_f32_16x16x32_bf16(xa, wi[nt], acc[nt], 0, 0, 0);
    if (t > 0) {
      __syncthreads();                   // h shuttle: write(t-1) -> read(t)
      bf16x8 ha0 = *(const bf16x8*)&hsh[wave][arow][kg * 8];
      bf16x8 ha1 = *(const bf16x8*)&hsh[wave][arow][32 + kg * 8];
      #pragma unroll
      for (int nt = 0; nt < 16; nt++) {
        bf16x8 wb = *(const bf16x8*)&whf[(nt * 64 + lane) * 8 + zo];
        acc[nt] = __builtin_amdgcn_mfma_f32_16x16x32_bf16(ha0, wb, acc[nt], 0, 0, 0);
      }
      #pragma unroll
      for (int nt = 0; nt < 16; nt++) {
        bf16x8 wb = *(const bf16x8*)&whf[((16 + nt) * 64 + lane) * 8 + zo];
        acc[nt] = __builtin_amdgcn_mfma_f32_16x16x32_bf16(ha1, wb, acc[nt], 0, 0, 0);
      }
    }
    // gates: seq = kg*4+i, hidden j = arow*4+njt. Common-denominator forms:
    // c = (cprev*B + (eg-1)*A) / (A*B),  A=1+e^-f, B=(1+e^-i)(e^2g+1)
    // h = (ec-1) / ((ec+1)(1+e^-o)),     ec=e^2c      [7 trans vs 10]
    #pragma unroll
    for (int i = 0; i < 4; i++) {
      float hq[4];
      #pragma unroll
      for (int njt = 0; njt < 4; njt++) {
        float iv = acc[njt][i], fv = acc[njt + 4][i];
        float gv = acc[njt + 8][i], ov = acc[njt + 12][i];
        float cpv = cst[i * 4 + njt];
        float ei = __expf(-iv), ef = __expf(-fv);
        float eg = __expf(2.0f * gv), eo = __expf(-ov);
        float A = 1.0f + ef;
        float B = (1.0f + ei) * (eg + 1.0f);
        float c = fmaf(cpv, B, (eg - 1.0f) * A) * rcp_f(A * B);
        cst[i * 4 + njt] = c;
        float ec = __expf(2.0f * c);
        hq[njt] = (ec - 1.0f) * rcp_f((ec + 1.0f) * (1.0f + eo));
      }
      if (t < TT - 1) {
        unsigned int p0 = cvt_pk(hq[0], hq[1]);
        unsigned int p1 = cvt_pk(hq[2], hq[3]);
        *(uint2*)&hsh[wave][kg * 4 + i][arow * 4] = make_uint2(p0, p1);
      } else {
        *(float4*)&hout[(size_t)(seq_base + kg * 4 + i) * HH + arow * 4] =
            (float4){hq[0], hq[1], hq[2], hq[3]};
      }
    }
  }
}

// ---------------- K_prep: layer-2 weights transposed into ws ----------------
// wt layout (all fp32): [0..767] lin_w^T [k][s]; [768..779] lin_b;
// [784..1935] mp1_w^T [c][o=32]; [1936..1967] mp1_b;
// [1968..5807] mp2_w^T [c][o=40]; [5808..5847] mp2_b.
__global__ void k_prep(const float* __restrict__ lw, const float* __restrict__ lb,
                       const float* __restrict__ w1, const float* __restrict__ b1,
                       const float* __restrict__ w2, const float* __restrict__ b2,
                       float* __restrict__ wt) {
  int tid = threadIdx.x;
  for (int i = tid; i < 768; i += 256) { int k = i / 12, s = i % 12; wt[i] = lw[s * 64 + k]; }
  if (tid < 12) wt[768 + tid] = lb[tid];
  for (int i = tid; i < 1152; i += 256) { int c = i / 32, o = i % 32; wt[784 + i] = w1[o * 36 + c]; }
  if (tid < 32) wt[1936 + tid] = b1[tid];
  for (int i = tid; i < 3840; i += 256) { int c = i / 40, o = i % 40; wt[1968 + i] = w2[o * 96 + c]; }
  if (tid < 40) wt[5808 + tid] = b2[tid];
}

// ---------------- K4: hj[b][s][n] = h[b*1000+n] . lin_w2[s] + lin_b2[s] -----
__global__ void k_hj(const float* __restrict__ h, const float* __restrict__ wt,
                     float* __restrict__ hj) {
  int id = blockIdx.x * 256 + threadIdx.x;     // (b,n), 64000 total
  int b = id / NNODE, n = id % NNODE;
  const float* hr = h + (size_t)id * HH;
  float hv[HH];
  #pragma unroll
  for (int k = 0; k < HH; k += 4) {
    float4 t4 = *(const float4*)(hr + k);
    hv[k] = t4.x; hv[k + 1] = t4.y; hv[k + 2] = t4.z; hv[k + 3] = t4.w;
  }
  float acc[12];
  #pragma unroll
  for (int s = 0; s < 12; s++) acc[s] = wt[768 + s];
  for (int k = 0; k < HH; k++) {
    float hvk = hv[k];
    #pragma unroll
    for (int s = 0; s < 12; s++) acc[s] = fmaf(hvk, wt[k * 12 + s], acc[s]);  // uniform -> SGPR
  }
  #pragma unroll
  for (int s = 0; s < 12; s++) hj[(size_t)(b * 12 + s) * NNODE + n] = acc[s];
}

// ---------------- K5/K7: mixprop propagation (gdep=2) -----------------------
// block = b*C + c. ho[b][d*C+c][:] for d=0,1,2 with h_{k+1}=0.05*x0+0.95*A h_k.
__global__ void k_prop(const float* __restrict__ hin, const int2* __restrict__ pae,
                       float* __restrict__ ho, int C) {
  int blk = blockIdx.x;
  int b = blk / C, c = blk % C;
  __shared__ float r0[NNODE], r1[NNODE];
  int tid = threadIdx.x;
  const float* src = hin + (size_t)(b * C + c) * NNODE;
  float* dst = ho + (size_t)(b * 3 * C) * NNODE;
  for (int n = tid; n < NNODE; n += 256) {
    float vv = src[n]; r0[n] = vv; dst[(size_t)c * NNODE + n] = vv;
  }
  __syncthreads();
  for (int n = tid; n < NNODE; n += 256) {
    const int2* pa = pae + n * EPR;
    float s = 0.f;
    #pragma unroll
    for (int e = 0; e < EPR; e++) { int2 p = pa[e]; s = fmaf(__int_as_float(p.y), r0[p.x], s); }
    float h1 = 0.05f * r0[n] + 0.95f * s;
    r1[n] = h1; dst[(size_t)(C + c) * NNODE + n] = h1;
  }
  __syncthreads();
  for (int n = tid; n < NNODE; n += 256) {
    const int2* pa = pae + n * EPR;
    float s = 0.f;
    #pragma unroll
    for (int e = 0; e < EPR; e++) { int2 p = pa[e]; s = fmaf(__int_as_float(p.y), r1[p.x], s); }
    dst[(size_t)(2 * C + c) * NNODE + n] = 0.05f * r0[n] + 0.95f * s;
  }
}

// ---------------- K6/K8: channel projection (uniform weights -> SGPR) -------
template <int CIN, int COUT>
__global__ void k_proj(const float* __restrict__ hin, const float* __restrict__ wt,
                       const float* __restrict__ bb, float* __restrict__ out, int relu) {
  int id = blockIdx.x * 256 + threadIdx.x;   // (b,n)
  int b = id / NNODE, n = id % NNODE;
  float acc[COUT];
  #pragma unroll
  for (int o = 0; o < COUT; o++) acc[o] = bb[o];
  for (int c = 0; c < CIN; c++) {
    float hv = hin[(size_t)(b * CIN + c) * NNODE + n];
    #pragma unroll
    for (int o = 0; o < COUT; o++) acc[o] = fmaf(hv, wt[c * COUT + o], acc[o]);
  }
  #pragma unroll
  for (int o = 0; o < COUT; o++) {
    float vv = acc[o];
    if (relu) vv = fmaxf(vv, 0.f);
    out[(size_t)(b * COUT + o) * NNODE + n] = vv;
  }
}

// ---------------- K9: layernorm stats over (40,1000) per batch --------------
__global__ void k_lnstat(const float* __restrict__ hj2, float* __restrict__ stat) {
  int b = blockIdx.x, tid = threadIdx.x, lane = tid & 63, wave = tid >> 6;
  const float* p = hj2 + (size_t)b * DD * NNODE;
  float s = 0.f, q = 0.f;
  for (int i = tid; i < DD * NNODE; i += 256) { float vv = p[i]; s += vv; q = fmaf(vv, vv, q); }
  for (int off = 32; off; off >>= 1) { s += __shfl_down(s, off); q += __shfl_down(q, off); }
  __shared__ float ss[4], sq[4];
  if (lane == 0) { ss[wave] = s; sq[wave] = q; }
  __syncthreads();
  if (tid == 0) {
    const float invN = 1.0f / (float)(DD * NNODE);
    float S = ss[0] + ss[1] + ss[2] + ss[3];
    float Q = sq[0] + sq[1] + sq[2] + sq[3];
    float mu = S * invN;
    float var = Q * invN - mu * mu;
    stat[2 * b] = mu; stat[2 * b + 1] = __builtin_amdgcn_rsqf(var + 1e-5f);
  }
}

// ---------------- K10: apply LN + transpose + fp32 out ----------------------
__global__ void k_lnapply(const float* __restrict__ hj2, const float* __restrict__ stat,
                          const float* __restrict__ gamma, const float* __restrict__ beta,
                          float* __restrict__ out) {
  int id = blockIdx.x * 256 + threadIdx.x;   // (b,n)
  int b = id / NNODE, n = id % NNODE;
  float mu = stat[2 * b], rstd = stat[2 * b + 1];
  size_t obase = (size_t)b * (NNODE * DD) + (size_t)n * DD;
  #pragma unroll
  for (int d0 = 0; d0 < DD / 4; d0++) {
    float tt[4];
    #pragma unroll
    for (int q = 0; q < 4; q++) {
      int d = d0 * 4 + q;
      float h0 = hj2[(size_t)(b * DD + d) * NNODE + n];
      tt[q] = (h0 - mu) * rstd * gamma[d * NNODE + n] + beta[d * NNODE + n];
    }
    *(float4*)(out + obase + d0 * 4) = (float4){tt[0], tt[1], tt[2], tt[3]};
  }
}

// ---------------- workspace layout (fp32 words) -----------------------------
// 0        m1(40000) | 40000 m2(40000) | 80000 pae(21000 int2 = 42000 words)
// 122000   h_lstm(4.096M)  [reused by ho2 after K4]
// 4218000  hj(768000) | 4986000 ho1(2.304M) | 7290000 o1(2.048M)
// 122000   ho2(6.144M)  [overlaps dead h_lstm/hj/ho1; ends 6266000 < 7290000]
// 9338000  hj2(2.56M) | 11898000 stat(128) | 11898128 wt(5848)   total ~47.6 MB
#define OFF_M1   0
#define OFF_M2   40000
#define OFF_PAE  80000
#define OFF_H    122000
#define OFF_HJ   4218000
#define OFF_HO1  4986000
#define OFF_O1   7290000
#define OFF_HO2  122000
#define OFF_HJ2  9338000
#define OFF_STAT 11898000
#define OFF_WT   11898128

extern "C" void kernel_launch(void* const* d_in, const int* in_sizes, int n_in,
                              void* d_out, int out_size, void* d_ws, size_t ws_size,
                              hipStream_t stream) {
  (void)in_sizes; (void)n_in; (void)out_size; (void)ws_size;
  const float* x     = (const float*)d_in[0];
  const float* emb1  = (const float*)d_in[1];
  const float* emb2  = (const float*)d_in[2];
  const float* l1w   = (const float*)d_in[3];
  const float* l1b   = (const float*)d_in[4];
  const float* l2w   = (const float*)d_in[5];
  const float* l2b   = (const float*)d_in[6];
  const float* Wih   = (const float*)d_in[7];
  const float* Whh   = (const float*)d_in[8];
  const float* bih   = (const float*)d_in[9];
  const float* bhh   = (const float*)d_in[10];
  const float* lin_w = (const float*)d_in[11];
  const float* lin_b = (const float*)d_in[12];
  const float* mp1w  = (const float*)d_in[13];
  const float* mp1b  = (const float*)d_in[14];
  const float* mp2w  = (const float*)d_in[15];
  const float* mp2b  = (const float*)d_in[16];
  const float* gamma = (const float*)d_in[17];
  const float* beta  = (const float*)d_in[18];

  float* ws   = (float*)d_ws;
  float* m1   = ws + OFF_M1;
  float* m2   = ws + OFF_M2;
  int2*  pae  = (int2*)(ws + OFF_PAE);
  float* hl   = ws + OFF_H;
  float* hj   = ws + OFF_HJ;
  float* ho1  = ws + OFF_HO1;
  float* o1   = ws + OFF_O1;
  float* ho2  = ws + OFF_HO2;
  float* hj2  = ws + OFF_HJ2;
  float* stat = ws + OFF_STAT;
  float* wt   = ws + OFF_WT;

  k_m1m2<<<dim3(313), dim3(256), 0, stream>>>(emb1, emb2, l1w, l1b, l2w, l2b, m1, m2);
  k_prep<<<dim3(1), dim3(256), 0, stream>>>(lin_w + 1536, lin_b + 24, mp1w + 2304, mp1b + 64,
                                            mp2w + 7680, mp2b + 80, wt);
  k_adj<<<dim3(NNODE), dim3(256), 0, stream>>>(m1, m2, pae);
  k_lstm<<<dim3(1000), dim3(256), 0, stream>>>(x, Wih, Whh, bih, bhh, hl);
  k_hj<<<dim3(250), dim3(256), 0, stream>>>(hl, wt, hj);
  k_prop<<<dim3(64 * 12), dim3(256), 0, stream>>>(hj, pae, ho1, 12);
  k_proj<36, 32><<<dim3(250), dim3(256), 0, stream>>>(ho1, wt + 784, wt + 1936, o1, 1);
  k_prop<<<dim3(64 * 32), dim3(256), 0, stream>>>(o1, pae, ho2, 32);
  k_proj<96, 40><<<dim3(250), dim3(256), 0, stream>>>(ho2, wt + 1968, wt + 5808, hj2, 0);
  k_lnstat<<<dim3(NB), dim3(256), 0, stream>>>(hj2, stat);
  k_lnapply<<<dim3(250), dim3(256), 0, stream>>>(hj2, stat, gamma + 80000, beta + 80000,
                                                 (float*)d_out);
}

// Round 9
// 313.657 us; speedup vs baseline: 1.5493x; 1.0084x over previous
//
#include <hip/hip_runtime.h>

// ---------------------------------------------------------------------------
// net_lstm: graph-constructor (topk-20 sparse adj) + per-node LSTM (bf16 MFMA)
//           + mixprop x2 (sparse gather + uniform-weight proj) + layernorm.
// Only layer j=2 of the 3 layers affects the output (reference overwrites h).
// ALL tensors are FLOAT32 on device. LSTM matmul in bf16 MFMA, rest fp32.
// NOTE: k_lstm is REGISTER-BOUND: occupancy follows actual unified VGPR+AGPR
// count. __launch_bounds__ min-waves MUST stay at 2 — (256,4) caps regs at
// 128 incl AGPRs -> 850 MB scratch spill, 2.5x slower (round-7, measured).
// ---------------------------------------------------------------------------

typedef unsigned short u16;
typedef __attribute__((ext_vector_type(8))) short bf16x8;   // 8 bf16 = 4 VGPR (MFMA A/B frag)
typedef __attribute__((ext_vector_type(4))) float fx4;      // MFMA C/D frag

#define NB 64          // batch
#define NNODE 1000
#define TT 12
#define FF 32
#define HH 64
#define DD 40
#define TOPK_ 20
#define EPR 21         // entries per adjacency row (topk + diagonal)

__device__ __forceinline__ float rcp_f(float x) { return __builtin_amdgcn_rcpf(x); }
__device__ __forceinline__ float tanh_f(float x) {          // NaN-safe: e>=0 always
  return fmaf(-2.0f, rcp_f(__expf(2.0f * x) + 1.0f), 1.0f);
}
__device__ __forceinline__ unsigned int cvt_pk(float lo, float hi) {
  unsigned int r;                                           // r = [bf16(hi)|bf16(lo)]
  asm("v_cvt_pk_bf16_f32 %0, %1, %2" : "=v"(r) : "v"(lo), "v"(hi));
  return r;
}
__device__ __forceinline__ bf16x8 cvt8(const float* p) {    // 8 fp32 -> bf16x8 (4 cvt_pk)
  union { unsigned int u[4]; bf16x8 v; } r;
  #pragma unroll
  for (int e = 0; e < 4; e++) r.u[e] = cvt_pk(p[2 * e], p[2 * e + 1]);
  return r.v;
}
__device__ __forceinline__ bf16x8 cvt8v(float4 a, float4 b) {
  union { unsigned int u[4]; bf16x8 v; } r;
  r.u[0] = cvt_pk(a.x, a.y); r.u[1] = cvt_pk(a.z, a.w);
  r.u[2] = cvt_pk(b.x, b.y); r.u[3] = cvt_pk(b.z, b.w);
  return r.v;
}

// ---------------- K1: m1/m2 = tanh(3*(emb @ w^T + b)) -----------------------
__global__ void k_m1m2(const float* __restrict__ emb1, const float* __restrict__ emb2,
                       const float* __restrict__ w1, const float* __restrict__ b1,
                       const float* __restrict__ w2, const float* __restrict__ b2,
                       float* __restrict__ m1, float* __restrict__ m2) {
  int id = blockIdx.x * 256 + threadIdx.x;
  if (id >= 2 * NNODE * DD) return;
  int sel = id / (NNODE * DD);
  int r = id % (NNODE * DD);
  int i = r / DD, o = r % DD;
  const float* emb = sel ? emb2 : emb1;
  const float* w = sel ? w2 : w1;
  const float* bb = sel ? b2 : b1;
  float s = bb[o];
  for (int k = 0; k < DD; k++) s = fmaf(emb[i * DD + k], w[o * DD + k], s);
  (sel ? m2 : m1)[r] = tanh_f(3.0f * s);
}

// ---------------- K2: adjacency row + top-20 + normalize --------------------
// Selection: wave 0 only, scores in 16 regs/lane, 20 passes of __shfl_xor
// butterfly — zero barriers, static reg indices. Tie: value desc, idx asc.
__global__ void k_adj(const float* __restrict__ m1, const float* __restrict__ m2,
                      int2* __restrict__ pae) {
  int v = blockIdx.x, tid = threadIdx.x;
  __shared__ float arow[NNODE];
  __shared__ float m1v[DD], m2v[DD];
  if (tid < DD) { m1v[tid] = m1[v * DD + tid]; m2v[tid] = m2[v * DD + tid]; }
  __syncthreads();
  for (int w = tid; w < NNODE; w += 256) {
    float d1 = 0.f, d2 = 0.f;
    #pragma unroll 8
    for (int k = 0; k < DD; k++) {
      d1 = fmaf(m1v[k], m2[w * DD + k], d1);
      d2 = fmaf(m2v[k], m1[w * DD + k], d2);
    }
    arow[w] = fmaxf(tanh_f(3.0f * (d1 - d2)), 0.0f);
  }
  __syncthreads();
  if (tid >= 64) return;                 // selection: wave 0 only
  int l = tid;
  float rv[16];
  #pragma unroll
  for (int q = 0; q < 16; q++) {
    int idx = q * 64 + l;
    rv[q] = (idx < NNODE) ? arow[idx] : -2.f;
  }
  float rs = 1.f;                        // diagonal contributes 1
  float myv = 0.f; int myi = 0;          // lane l carries selected entry (l-1)
  #pragma unroll
  for (int sel = 0; sel < TOPK_; sel++) {
    float bv = rv[0]; int bi = l;
    #pragma unroll
    for (int q = 1; q < 16; q++) {
      int idx = q * 64 + l;
      if (rv[q] > bv) { bv = rv[q]; bi = idx; }   // ascending q => lowest idx on tie
    }
    #pragma unroll
    for (int off = 1; off < 64; off <<= 1) {
      float ov = __shfl_xor(bv, off); int oi = __shfl_xor(bi, off);
      if (ov > bv || (ov == bv && oi < bi)) { bv = ov; bi = oi; }
    }
    rs += bv;
    if (l == sel + 1) { myv = bv; myi = bi; }
    #pragma unroll
    for (int q = 0; q < 16; q++)
      if (q * 64 + l == bi) rv[q] = -2.f;         // invalidate winner
  }
  float inv = rcp_f(rs);
  if (l == 0)          pae[v * EPR] = make_int2(v, __float_as_int(inv));
  else if (l <= TOPK_) pae[v * EPR + l] = make_int2(myi, __float_as_int(myv * inv));
}

// ---------------- K3: LSTM (12 steps, bf16 MFMA) + fused hj epilogue --------
// 4 waves/block; wave owns 16 seqs. Column remap: logical col L=nt*16+c holds
// gate g=nt>>2, hidden j=c*4+(nt&3) => thread(c=arow) owns (seq kg*4+i,
// j=arow*4+njt) with i/f/g/o in the same lane. nt-loop restructured into 4
// njt-GROUPS (4 gate tiles -> gate math immediately) so only 16 AGPRs of
// accumulator are live (was 64) -> ~3 waves/SIMD. bias in LDS (-16 VGPR).
// hsh shuttle is WAVE-PRIVATE: DS ops are in-order per wave, so only a
// compiler fence (asm memory clobber) is needed between write(t)/read(t+1) —
// no __syncthreads in the main loop (waves decouple). Epilogue computes
// hj = h @ lin_w2^T + b directly (h never leaves registers): per-lane partial
// over its 4 j's, shfl_xor butterfly over 16 arow lanes, static select chain.
__global__ __launch_bounds__(256, 2)
void k_lstm(const float* __restrict__ x, const float* __restrict__ Wih,
            const float* __restrict__ Whh, const float* __restrict__ bih,
            const float* __restrict__ bhh, const float* __restrict__ wt,
            float* __restrict__ hj) {
  __shared__ __align__(16) u16 whf[2 * 16 * 64 * 8];  // Whh frags (32 KB)
  __shared__ __align__(16) u16 hsh[4][16][64];        // per-wave h shuttle (8 KB)
  __shared__ float lwsh[12 * 64];                     // lin_w2 [s][j] (3 KB)
  __shared__ float lbsh[12];
  __shared__ float bsh[256];                          // bih+bhh, frag-mapped (1 KB)
  int tid = threadIdx.x, wave = tid >> 6, lane = tid & 63;
  int arow = lane & 15, kg = lane >> 4;

  // stage Whh frags: frag(ks,nt,l,e) = Whh[row=(nt>>2)*64+(l&15)*4+(nt&3)][ks*32+(l>>4)*8+e]
  for (int cc = tid; cc < 2 * 16 * 64; cc += 256) {
    int l = cc & 63, t16 = cc >> 6, ks = t16 >> 4, nt = t16 & 15;
    int row = (nt >> 2) * 64 + (l & 15) * 4 + (nt & 3);
    *(bf16x8*)&whf[cc * 8] = cvt8(Whh + row * 64 + ks * 32 + (l >> 4) * 8);
  }
  for (int i = tid; i < 768; i += 256) { int s = i >> 6, j = i & 63; lwsh[i] = wt[j * 12 + s]; }
  if (tid < 12) lbsh[tid] = wt[768 + tid];
  {
    int nt = tid >> 4, c = tid & 15;
    int row = (nt >> 2) * 64 + c * 4 + (nt & 3);
    bsh[tid] = bih[row] + bhh[row];
  }
  __syncthreads();                                    // the ONLY block barrier

  bf16x8 wi[16];                                      // Wih fragments in registers
  #pragma unroll
  for (int nt = 0; nt < 16; nt++) {
    int row = (nt >> 2) * 64 + arow * 4 + (nt & 3);
    wi[nt] = cvt8(Wih + row * 32 + kg * 8);
  }

  int seq_base = blockIdx.x * 64 + wave * 16;
  const float* xb = x + (size_t)(seq_base + arow) * (TT * FF) + kg * 8;
  float cst[16];
  #pragma unroll
  for (int q = 0; q < 16; q++) cst[q] = 0.f;

  float4 xf0 = *(const float4*)(xb);                  // prefetch t=0
  float4 xf1 = *(const float4*)(xb + 4);

  auto STEP = [&](int t, bool first, float (&hq)[16]) {
    unsigned int zo = 0;                 // opaque zero: whf addrs loop-variant
    asm volatile("" : "+v"(zo));
    bf16x8 xa = cvt8v(xf0, xf1);
    if (t < TT - 1) {                    // prefetch x(t+1); hides under compute
      xf0 = *(const float4*)(xb + (t + 1) * FF);
      xf1 = *(const float4*)(xb + (t + 1) * FF + 4);
    }
    bf16x8 ha0 = {}, ha1 = {};
    if (!first) {
      asm volatile("" ::: "memory");     // reads stay after prev-step writes
      ha0 = *(const bf16x8*)&hsh[wave][arow][kg * 8];
      ha1 = *(const bf16x8*)&hsh[wave][arow][32 + kg * 8];
      asm volatile("" ::: "memory");     // this-step writes stay after reads
    }
    #pragma unroll
    for (int g = 0; g < 4; g++) {        // njt-group: 4 gate tiles, then gates
      float b0 = bsh[g * 16 + arow],       b1 = bsh[(g + 4) * 16 + arow];
      float b2 = bsh[(g + 8) * 16 + arow], b3 = bsh[(g + 12) * 16 + arow];
      fx4 ai = {b0, b0, b0, b0}, af = {b1, b1, b1, b1};
      fx4 ag = {b2, b2, b2, b2}, ao = {b3, b3, b3, b3};
      ai = __builtin_amdgcn_mfma_f32_16x16x32_bf16(xa, wi[g],      ai, 0, 0, 0);
      af = __builtin_amdgcn_mfma_f32_16x16x32_bf16(xa, wi[g + 4],  af, 0, 0, 0);
      ag = __builtin_amdgcn_mfma_f32_16x16x32_bf16(xa, wi[g + 8],  ag, 0, 0, 0);
      ao = __builtin_amdgcn_mfma_f32_16x16x32_bf16(xa, wi[g + 12], ao, 0, 0, 0);
      if (!first) {
        bf16x8 w0 = *(const bf16x8*)&whf[((g)      * 64 + lane) * 8 + zo];
        bf16x8 w1 = *(const bf16x8*)&whf[((g + 4)  * 64 + lane) * 8 + zo];
        bf16x8 w2 = *(const bf16x8*)&whf[((g + 8)  * 64 + lane) * 8 + zo];
        bf16x8 w3 = *(const bf16x8*)&whf[((g + 12) * 64 + lane) * 8 + zo];
        ai = __builtin_amdgcn_mfma_f32_16x16x32_bf16(ha0, w0, ai, 0, 0, 0);
        af = __builtin_amdgcn_mfma_f32_16x16x32_bf16(ha0, w1, af, 0, 0, 0);
        ag = __builtin_amdgcn_mfma_f32_16x16x32_bf16(ha0, w2, ag, 0, 0, 0);
        ao = __builtin_amdgcn_mfma_f32_16x16x32_bf16(ha0, w3, ao, 0, 0, 0);
        w0 = *(const bf16x8*)&whf[((16 + g)      * 64 + lane) * 8 + zo];
        w1 = *(const bf16x8*)&whf[((16 + g + 4)  * 64 + lane) * 8 + zo];
        w2 = *(const bf16x8*)&whf[((16 + g + 8)  * 64 + lane) * 8 + zo];
        w3 = *(const bf16x8*)&whf[((16 + g + 12) * 64 + lane) * 8 + zo];
        ai = __builtin_amdgcn_mfma_f32_16x16x32_bf16(ha1, w0, ai, 0, 0, 0);
        af = __builtin_amdgcn_mfma_f32_16x16x32_bf16(ha1, w1, af, 0, 0, 0);
        ag = __builtin_amdgcn_mfma_f32_16x16x32_bf16(ha1, w2, ag, 0, 0, 0);
        ao = __builtin_amdgcn_mfma_f32_16x16x32_bf16(ha1, w3, ao, 0, 0, 0);
      }
      // gates for (seq=kg*4+i, j=arow*4+g): c=(cp*B+(eg-1)*A)*rcp(A*B),
      // A=1+e^-f, B=(1+e^-i)(e^2g+1); h=(ec-1)*rcp((ec+1)(1+e^-o))
      #pragma unroll
      for (int i = 0; i < 4; i++) {
        float iv = ai[i], fv = af[i], gv = ag[i], ov = ao[i];
        float cpv = cst[i * 4 + g];
        float ei = __expf(-iv), ef = __expf(-fv);
        float eg = __expf(2.0f * gv), eo = __expf(-ov);
        float A = 1.0f + ef;
        float B = (1.0f + ei) * (eg + 1.0f);
        float c = fmaf(cpv, B, (eg - 1.0f) * A) * rcp_f(A * B);
        cst[i * 4 + g] = c;
        float ec = __expf(2.0f * c);
        hq[i * 4 + g] = (ec - 1.0f) * rcp_f((ec + 1.0f) * (1.0f + eo));
      }
    }
  };

  #pragma unroll 1
  for (int t = 0; t < TT - 1; t++) {
    float hq[16];
    STEP(t, t == 0, hq);
    #pragma unroll
    for (int i = 0; i < 4; i++) {
      unsigned int p0 = cvt_pk(hq[i * 4 + 0], hq[i * 4 + 1]);
      unsigned int p1 = cvt_pk(hq[i * 4 + 2], hq[i * 4 + 3]);
      *(uint2*)&hsh[wave][kg * 4 + i][arow * 4] = make_uint2(p0, p1);
    }
  }
  float hq[16];
  STEP(TT - 1, false, hq);               // final h stays in registers

  // fused hj: hj[b][s][n] = sum_j h[j]*lw[s][j] + lb[s]; reduce over arow lanes
  #pragma unroll
  for (int i = 0; i < 4; i++) {
    float a[12];
    #pragma unroll
    for (int s = 0; s < 12; s++) a[s] = 0.f;
    #pragma unroll
    for (int njt = 0; njt < 4; njt++) {
      float hv = hq[i * 4 + njt];
      #pragma unroll
      for (int s = 0; s < 12; s++)
        a[s] = fmaf(hv, lwsh[s * 64 + arow * 4 + njt], a[s]);
    }
    #pragma unroll
    for (int off = 1; off < 16; off <<= 1) {
      #pragma unroll
      for (int s = 0; s < 12; s++) a[s] += __shfl_xor(a[s], off);
    }
    float outv = a[0];                   // static select chain (rule #20)
    #pragma unroll
    for (int s = 1; s < 12; s++) outv = (arow == s) ? a[s] : outv;
    if (arow < 12) {
      int gseq = seq_base + kg * 4 + i;
      int bb = gseq / 1000, nn = gseq - bb * 1000;
      hj[(size_t)(bb * 12 + arow) * NNODE + nn] = outv + lbsh[arow];
    }
  }
}

// ---------------- K_prep: layer-2 weights transposed into ws ----------------
// wt layout (all fp32): [0..767] lin_w^T [k][s]; [768..779] lin_b;
// [784..1935] mp1_w^T [c][o=32]; [1936..1967] mp1_b;
// [1968..5807] mp2_w^T [c][o=40]; [5808..5847] mp2_b.
__global__ void k_prep(const float* __restrict__ lw, const float* __restrict__ lb,
                       const float* __restrict__ w1, const float* __restrict__ b1,
                       const float* __restrict__ w2, const float* __restrict__ b2,
                       float* __restrict__ wt) {
  int tid = threadIdx.x;
  for (int i = tid; i < 768; i += 256) { int k = i / 12, s = i % 12; wt[i] = lw[s * 64 + k]; }
  if (tid < 12) wt[768 + tid] = lb[tid];
  for (int i = tid; i < 1152; i += 256) { int c = i / 32, o = i % 32; wt[784 + i] = w1[o * 36 + c]; }
  if (tid < 32) wt[1936 + tid] = b1[tid];
  for (int i = tid; i < 3840; i += 256) { int c = i / 40, o = i % 40; wt[1968 + i] = w2[o * 96 + c]; }
  if (tid < 40) wt[5808 + tid] = b2[tid];
}

// ---------------- K5/K7: mixprop propagation (gdep=2) -----------------------
__global__ void k_prop(const float* __restrict__ hin, const int2* __restrict__ pae,
                       float* __restrict__ ho, int C) {
  int blk = blockIdx.x;
  int b = blk / C, c = blk % C;
  __shared__ float r0[NNODE], r1[NNODE];
  int tid = threadIdx.x;
  const float* src = hin + (size_t)(b * C + c) * NNODE;
  float* dst = ho + (size_t)(b * 3 * C) * NNODE;
  for (int n = tid; n < NNODE; n += 256) {
    float vv = src[n]; r0[n] = vv; dst[(size_t)c * NNODE + n] = vv;
  }
  __syncthreads();
  for (int n = tid; n < NNODE; n += 256) {
    const int2* pa = pae + n * EPR;
    float s = 0.f;
    #pragma unroll
    for (int e = 0; e < EPR; e++) { int2 p = pa[e]; s = fmaf(__int_as_float(p.y), r0[p.x], s); }
    float h1 = 0.05f * r0[n] + 0.95f * s;
    r1[n] = h1; dst[(size_t)(C + c) * NNODE + n] = h1;
  }
  __syncthreads();
  for (int n = tid; n < NNODE; n += 256) {
    const int2* pa = pae + n * EPR;
    float s = 0.f;
    #pragma unroll
    for (int e = 0; e < EPR; e++) { int2 p = pa[e]; s = fmaf(__int_as_float(p.y), r1[p.x], s); }
    dst[(size_t)(2 * C + c) * NNODE + n] = 0.05f * r0[n] + 0.95f * s;
  }
}

// ---------------- K6/K8: channel projection (uniform weights -> SGPR) -------
template <int CIN, int COUT>
__global__ void k_proj(const float* __restrict__ hin, const float* __restrict__ wt,
                       const float* __restrict__ bb, float* __restrict__ out, int relu) {
  int id = blockIdx.x * 256 + threadIdx.x;   // (b,n)
  int b = id / NNODE, n = id % NNODE;
  float acc[COUT];
  #pragma unroll
  for (int o = 0; o < COUT; o++) acc[o] = bb[o];
  for (int c = 0; c < CIN; c++) {
    float hv = hin[(size_t)(b * CIN + c) * NNODE + n];
    #pragma unroll
    for (int o = 0; o < COUT; o++) acc[o] = fmaf(hv, wt[c * COUT + o], acc[o]);
  }
  #pragma unroll
  for (int o = 0; o < COUT; o++) {
    float vv = acc[o];
    if (relu) vv = fmaxf(vv, 0.f);
    out[(size_t)(b * COUT + o) * NNODE + n] = vv;
  }
}

// ---------------- K9: layernorm stats over (40,1000) per batch --------------
__global__ void k_lnstat(const float* __restrict__ hj2, float* __restrict__ stat) {
  int b = blockIdx.x, tid = threadIdx.x, lane = tid & 63, wave = tid >> 6;
  const float* p = hj2 + (size_t)b * DD * NNODE;
  float s = 0.f, q = 0.f;
  for (int i = tid; i < DD * NNODE; i += 256) { float vv = p[i]; s += vv; q = fmaf(vv, vv, q); }
  for (int off = 32; off; off >>= 1) { s += __shfl_down(s, off); q += __shfl_down(q, off); }
  __shared__ float ss[4], sq[4];
  if (lane == 0) { ss[wave] = s; sq[wave] = q; }
  __syncthreads();
  if (tid == 0) {
    const float invN = 1.0f / (float)(DD * NNODE);
    float S = ss[0] + ss[1] + ss[2] + ss[3];
    float Q = sq[0] + sq[1] + sq[2] + sq[3];
    float mu = S * invN;
    float var = Q * invN - mu * mu;
    stat[2 * b] = mu; stat[2 * b + 1] = __builtin_amdgcn_rsqf(var + 1e-5f);
  }
}

// ---------------- K10: apply LN + transpose + fp32 out ----------------------
__global__ void k_lnapply(const float* __restrict__ hj2, const float* __restrict__ stat,
                          const float* __restrict__ gamma, const float* __restrict__ beta,
                          float* __restrict__ out) {
  int id = blockIdx.x * 256 + threadIdx.x;   // (b,n)
  int b = id / NNODE, n = id % NNODE;
  float mu = stat[2 * b], rstd = stat[2 * b + 1];
  size_t obase = (size_t)b * (NNODE * DD) + (size_t)n * DD;
  #pragma unroll
  for (int d0 = 0; d0 < DD / 4; d0++) {
    float tt[4];
    #pragma unroll
    for (int q = 0; q < 4; q++) {
      int d = d0 * 4 + q;
      float h0 = hj2[(size_t)(b * DD + d) * NNODE + n];
      tt[q] = (h0 - mu) * rstd * gamma[d * NNODE + n] + beta[d * NNODE + n];
    }
    *(float4*)(out + obase + d0 * 4) = (float4){tt[0], tt[1], tt[2], tt[3]};
  }
}

// ---------------- workspace layout (fp32 words) -----------------------------
// 0        m1(40000) | 40000 m2(40000) | 80000 pae(21000 int2 = 42000 words)
// 122000   ho2(6.144M) [region reused; h_lstm eliminated]
// 4218000  hj(768000) | 4986000 ho1(2.304M) | 7290000 o1(2.048M)
// 9338000  hj2(2.56M) | 11898000 stat(128) | 11898128 wt(5848)   total ~47.6 MB
#define OFF_M1   0
#define OFF_M2   40000
#define OFF_PAE  80000
#define OFF_HJ   4218000
#define OFF_HO1  4986000
#define OFF_O1   7290000
#define OFF_HO2  122000
#define OFF_HJ2  9338000
#define OFF_STAT 11898000
#define OFF_WT   11898128

extern "C" void kernel_launch(void* const* d_in, const int* in_sizes, int n_in,
                              void* d_out, int out_size, void* d_ws, size_t ws_size,
                              hipStream_t stream) {
  (void)in_sizes; (void)n_in; (void)out_size; (void)ws_size;
  const float* x     = (const float*)d_in[0];
  const float* emb1  = (const float*)d_in[1];
  const float* emb2  = (const float*)d_in[2];
  const float* l1w   = (const float*)d_in[3];
  const float* l1b   = (const float*)d_in[4];
  const float* l2w   = (const float*)d_in[5];
  const float* l2b   = (const float*)d_in[6];
  const float* Wih   = (const float*)d_in[7];
  const float* Whh   = (const float*)d_in[8];
  const float* bih   = (const float*)d_in[9];
  const float* bhh   = (const float*)d_in[10];
  const float* lin_w = (const float*)d_in[11];
  const float* lin_b = (const float*)d_in[12];
  const float* mp1w  = (const float*)d_in[13];
  const float* mp1b  = (const float*)d_in[14];
  const float* mp2w  = (const float*)d_in[15];
  const float* mp2b  = (const float*)d_in[16];
  const float* gamma = (const float*)d_in[17];
  const float* beta  = (const float*)d_in[18];

  float* ws   = (float*)d_ws;
  float* m1   = ws + OFF_M1;
  float* m2   = ws + OFF_M2;
  int2*  pae  = (int2*)(ws + OFF_PAE);
  float* hj   = ws + OFF_HJ;
  float* ho1  = ws + OFF_HO1;
  float* o1   = ws + OFF_O1;
  float* ho2  = ws + OFF_HO2;
  float* hj2  = ws + OFF_HJ2;
  float* stat = ws + OFF_STAT;
  float* wt   = ws + OFF_WT;

  k_m1m2<<<dim3(313), dim3(256), 0, stream>>>(emb1, emb2, l1w, l1b, l2w, l2b, m1, m2);
  k_prep<<<dim3(1), dim3(256), 0, stream>>>(lin_w + 1536, lin_b + 24, mp1w + 2304, mp1b + 64,
                                            mp2w + 7680, mp2b + 80, wt);
  k_adj<<<dim3(NNODE), dim3(256), 0, stream>>>(m1, m2, pae);
  k_lstm<<<dim3(1000), dim3(256), 0, stream>>>(x, Wih, Whh, bih, bhh, wt, hj);
  k_prop<<<dim3(64 * 12), dim3(256), 0, stream>>>(hj, pae, ho1, 12);
  k_proj<36, 32><<<dim3(250), dim3(256), 0, stream>>>(ho1, wt + 784, wt + 1936, o1, 1);
  k_prop<<<dim3(64 * 32), dim3(256), 0, stream>>>(o1, pae, ho2, 32);
  k_proj<96, 40><<<dim3(250), dim3(256), 0, stream>>>(ho2, wt + 1968, wt + 5808, hj2, 0);
  k_lnstat<<<dim3(NB), dim3(256), 0, stream>>>(hj2, stat);
  k_lnapply<<<dim3(250), dim3(256), 0, stream>>>(hj2, stat, gamma + 80000, beta + 80000,
                                                 (float*)d_out);
}

// Round 11
// 307.333 us; speedup vs baseline: 1.5812x; 1.0206x over previous
//
#include <hip/hip_runtime.h>

// ---------------------------------------------------------------------------
// net_lstm: graph-constructor (topk-20 sparse adj) + per-node LSTM (bf16 MFMA)
//           + mixprop x2 (sparse gather + uniform-weight proj) + layernorm.
// Only layer j=2 of the 3 layers affects the output (reference overwrites h).
// ALL tensors are FLOAT32 on device. LSTM matmul in bf16 MFMA, rest fp32.
// k_lstm design notes (measured):
//  - REGISTER/ILP-bound: 16 independent accumulators (64 AGPR) + 48
//    back-to-back MFMAs per step beat a 16-AGPR low-ILP variant by 10%
//    (r8 95.8us vs r9 105.5us). Per-wave ILP is the lever, not wave count.
//  - __launch_bounds__ min-waves MUST stay 2: (256,4) caps regs at 128 incl
//    AGPRs -> 850 MB scratch spill, 2.5x slower (r7, measured).
//  - r10's raw asm("v_exp_f32") + weight pre-scaling produced zero output
//    (failed launch or miscompile) — keep __expf; no hand-rolled trans asm.
// ---------------------------------------------------------------------------

typedef unsigned short u16;
typedef __attribute__((ext_vector_type(8))) short bf16x8;   // 8 bf16 = 4 VGPR (MFMA A/B frag)
typedef __attribute__((ext_vector_type(4))) float fx4;      // MFMA C/D frag

#define NB 64          // batch
#define NNODE 1000
#define TT 12
#define FF 32
#define HH 64
#define DD 40
#define TOPK_ 20
#define EPR 21         // entries per adjacency row (topk + diagonal)

__device__ __forceinline__ float rcp_f(float x) { return __builtin_amdgcn_rcpf(x); }
__device__ __forceinline__ float tanh_f(float x) {          // NaN-safe: e>=0 always
  return fmaf(-2.0f, rcp_f(__expf(2.0f * x) + 1.0f), 1.0f);
}
__device__ __forceinline__ unsigned int cvt_pk(float lo, float hi) {
  unsigned int r;                                           // r = [bf16(hi)|bf16(lo)]
  asm("v_cvt_pk_bf16_f32 %0, %1, %2" : "=v"(r) : "v"(lo), "v"(hi));
  return r;
}
__device__ __forceinline__ bf16x8 cvt8(const float* p) {    // 8 fp32 -> bf16x8 (4 cvt_pk)
  union { unsigned int u[4]; bf16x8 v; } r;
  #pragma unroll
  for (int e = 0; e < 4; e++) r.u[e] = cvt_pk(p[2 * e], p[2 * e + 1]);
  return r.v;
}
__device__ __forceinline__ bf16x8 cvt8v(float4 a, float4 b) {
  union { unsigned int u[4]; bf16x8 v; } r;
  r.u[0] = cvt_pk(a.x, a.y); r.u[1] = cvt_pk(a.z, a.w);
  r.u[2] = cvt_pk(b.x, b.y); r.u[3] = cvt_pk(b.z, b.w);
  return r.v;
}

// ---------------- K1: m1/m2 = tanh(3*(emb @ w^T + b)) -----------------------
__global__ void k_m1m2(const float* __restrict__ emb1, const float* __restrict__ emb2,
                       const float* __restrict__ w1, const float* __restrict__ b1,
                       const float* __restrict__ w2, const float* __restrict__ b2,
                       float* __restrict__ m1, float* __restrict__ m2) {
  int id = blockIdx.x * 256 + threadIdx.x;
  if (id >= 2 * NNODE * DD) return;
  int sel = id / (NNODE * DD);
  int r = id % (NNODE * DD);
  int i = r / DD, o = r % DD;
  const float* emb = sel ? emb2 : emb1;
  const float* w = sel ? w2 : w1;
  const float* bb = sel ? b2 : b1;
  float s = bb[o];
  for (int k = 0; k < DD; k++) s = fmaf(emb[i * DD + k], w[o * DD + k], s);
  (sel ? m2 : m1)[r] = tanh_f(3.0f * s);
}

// ---------------- K2: adjacency row + top-20 + normalize --------------------
// Selection: wave 0 only, scores in 16 regs/lane, 20 passes of __shfl_xor
// butterfly — zero barriers, static reg indices. Tie: value desc, idx asc.
__global__ void k_adj(const float* __restrict__ m1, const float* __restrict__ m2,
                      int2* __restrict__ pae) {
  int v = blockIdx.x, tid = threadIdx.x;
  __shared__ float arow[NNODE];
  __shared__ float m1v[DD], m2v[DD];
  if (tid < DD) { m1v[tid] = m1[v * DD + tid]; m2v[tid] = m2[v * DD + tid]; }
  __syncthreads();
  for (int w = tid; w < NNODE; w += 256) {
    float d1 = 0.f, d2 = 0.f;
    #pragma unroll 8
    for (int k = 0; k < DD; k++) {
      d1 = fmaf(m1v[k], m2[w * DD + k], d1);
      d2 = fmaf(m2v[k], m1[w * DD + k], d2);
    }
    arow[w] = fmaxf(tanh_f(3.0f * (d1 - d2)), 0.0f);
  }
  __syncthreads();
  if (tid >= 64) return;                 // selection: wave 0 only
  int l = tid;
  float rv[16];
  #pragma unroll
  for (int q = 0; q < 16; q++) {
    int idx = q * 64 + l;
    rv[q] = (idx < NNODE) ? arow[idx] : -2.f;
  }
  float rs = 1.f;                        // diagonal contributes 1
  float myv = 0.f; int myi = 0;          // lane l carries selected entry (l-1)
  #pragma unroll
  for (int sel = 0; sel < TOPK_; sel++) {
    float bv = rv[0]; int bi = l;
    #pragma unroll
    for (int q = 1; q < 16; q++) {
      int idx = q * 64 + l;
      if (rv[q] > bv) { bv = rv[q]; bi = idx; }   // ascending q => lowest idx on tie
    }
    #pragma unroll
    for (int off = 1; off < 64; off <<= 1) {
      float ov = __shfl_xor(bv, off); int oi = __shfl_xor(bi, off);
      if (ov > bv || (ov == bv && oi < bi)) { bv = ov; bi = oi; }
    }
    rs += bv;
    if (l == sel + 1) { myv = bv; myi = bi; }
    #pragma unroll
    for (int q = 0; q < 16; q++)
      if (q * 64 + l == bi) rv[q] = -2.f;         // invalidate winner
  }
  float inv = rcp_f(rs);
  if (l == 0)          pae[v * EPR] = make_int2(v, __float_as_int(inv));
  else if (l <= TOPK_) pae[v * EPR + l] = make_int2(myi, __float_as_int(myv * inv));
}

// ---------------- K3: LSTM (12 steps, bf16 MFMA) + fused hj epilogue --------
// 4 waves/block; wave owns 16 seqs. Column remap: logical col L=nt*16+c holds
// gate g=nt>>2, hidden j=c*4+(nt&3) => thread(c=arow) owns (seq kg*4+i,
// j=arow*4+njt) with i/f/g/o in the same lane (tiles njt,njt+4,+8,+12).
// Full-ILP inner loop: 16 independent accumulators, 48 MFMAs back-to-back,
// gates once per step (r8 structure, fastest measured). hsh shuttle is
// WAVE-PRIVATE: DS ops in-order per wave => compiler fences only, no block
// barrier in the main loop. Epilogue: hj = h @ lin_w2^T + b with h still in
// registers (shfl_xor butterfly over the 16 arow lanes, static select chain).
__global__ __launch_bounds__(256, 2)
void k_lstm(const float* __restrict__ x, const float* __restrict__ Wih,
            const float* __restrict__ Whh, const float* __restrict__ bih,
            const float* __restrict__ bhh, const float* __restrict__ wt,
            float* __restrict__ hj) {
  __shared__ __align__(16) u16 whf[2 * 16 * 64 * 8];  // Whh frags (32 KB)
  __shared__ __align__(16) u16 hsh[4][16][64];        // per-wave h shuttle (8 KB)
  __shared__ float lwsh[12 * 64];                     // lin_w2 [s][j] (3 KB)
  __shared__ float lbsh[12];
  int tid = threadIdx.x, wave = tid >> 6, lane = tid & 63;
  int arow = lane & 15, kg = lane >> 4;

  // stage Whh frags: frag(ks,nt,l,e) = Whh[row=(nt>>2)*64+(l&15)*4+(nt&3)][ks*32+(l>>4)*8+e]
  for (int cc = tid; cc < 2 * 16 * 64; cc += 256) {
    int l = cc & 63, t16 = cc >> 6, ks = t16 >> 4, nt = t16 & 15;
    int row = (nt >> 2) * 64 + (l & 15) * 4 + (nt & 3);
    *(bf16x8*)&whf[cc * 8] = cvt8(Whh + row * 64 + ks * 32 + (l >> 4) * 8);
  }
  for (int i = tid; i < 768; i += 256) { int s = i >> 6, j = i & 63; lwsh[i] = wt[j * 12 + s]; }
  if (tid < 12) lbsh[tid] = wt[768 + tid];
  __syncthreads();                                    // the ONLY block barrier

  bf16x8 wi[16];                                      // Wih fragments in registers
  float biasv[16];
  #pragma unroll
  for (int nt = 0; nt < 16; nt++) {
    int row = (nt >> 2) * 64 + arow * 4 + (nt & 3);
    wi[nt] = cvt8(Wih + row * 32 + kg * 8);
    biasv[nt] = bih[row] + bhh[row];
  }

  int seq_base = blockIdx.x * 64 + wave * 16;
  const float* xb = x + (size_t)(seq_base + arow) * (TT * FF) + kg * 8;
  float cst[16];
  #pragma unroll
  for (int q = 0; q < 16; q++) cst[q] = 0.f;

  float4 xf0 = *(const float4*)(xb);                  // prefetch t=0
  float4 xf1 = *(const float4*)(xb + 4);

  auto STEP = [&](int t, bool first, float (&hq)[16]) {
    unsigned int zo = 0;                 // opaque zero: whf addrs loop-variant
    asm volatile("" : "+v"(zo));
    bf16x8 xa = cvt8v(xf0, xf1);
    if (t < TT - 1) {                    // prefetch x(t+1); hides under compute
      xf0 = *(const float4*)(xb + (t + 1) * FF);
      xf1 = *(const float4*)(xb + (t + 1) * FF + 4);
    }
    fx4 acc[16];
    #pragma unroll
    for (int nt = 0; nt < 16; nt++)
      acc[nt] = (fx4){biasv[nt], biasv[nt], biasv[nt], biasv[nt]};
    #pragma unroll
    for (int nt = 0; nt < 16; nt++)
      acc[nt] = __builtin_amdgcn_mfma_f32_16x16x32_bf16(xa, wi[nt], acc[nt], 0, 0, 0);
    if (!first) {
      asm volatile("" ::: "memory");     // reads stay after prev-step writes
      bf16x8 ha0 = *(const bf16x8*)&hsh[wave][arow][kg * 8];
      bf16x8 ha1 = *(const bf16x8*)&hsh[wave][arow][32 + kg * 8];
      asm volatile("" ::: "memory");     // this-step writes stay after reads
      #pragma unroll
      for (int nt = 0; nt < 16; nt++) {
        bf16x8 wb = *(const bf16x8*)&whf[(nt * 64 + lane) * 8 + zo];
        acc[nt] = __builtin_amdgcn_mfma_f32_16x16x32_bf16(ha0, wb, acc[nt], 0, 0, 0);
      }
      #pragma unroll
      for (int nt = 0; nt < 16; nt++) {
        bf16x8 wb = *(const bf16x8*)&whf[((16 + nt) * 64 + lane) * 8 + zo];
        acc[nt] = __builtin_amdgcn_mfma_f32_16x16x32_bf16(ha1, wb, acc[nt], 0, 0, 0);
      }
    }
    // gates for (seq=kg*4+i, j=arow*4+njt). Common-denominator forms:
    // c=(cp*B+(eg-1)*A)*rcp(A*B), A=1+e^-f, B=(1+e^-i)(e^2g+1);
    // h=(ec-1)*rcp((ec+1)(1+e^-o)), ec=e^2c      [7 trans ops/unit]
    #pragma unroll
    for (int i = 0; i < 4; i++) {
      #pragma unroll
      for (int njt = 0; njt < 4; njt++) {
        float iv = acc[njt][i], fv = acc[njt + 4][i];
        float gv = acc[njt + 8][i], ov = acc[njt + 12][i];
        float cpv = cst[i * 4 + njt];
        float ei = __expf(-iv), ef = __expf(-fv);
        float eg = __expf(2.0f * gv), eo = __expf(-ov);
        float A = 1.0f + ef;
        float B = (1.0f + ei) * (eg + 1.0f);
        float c = fmaf(cpv, B, (eg - 1.0f) * A) * rcp_f(A * B);
        cst[i * 4 + njt] = c;
        float ec = __expf(2.0f * c);
        hq[i * 4 + njt] = (ec - 1.0f) * rcp_f((ec + 1.0f) * (1.0f + eo));
      }
    }
  };

  #pragma unroll 1
  for (int t = 0; t < TT - 1; t++) {
    float hq[16];
    STEP(t, t == 0, hq);
    #pragma unroll
    for (int i = 0; i < 4; i++) {
      unsigned int p0 = cvt_pk(hq[i * 4 + 0], hq[i * 4 + 1]);
      unsigned int p1 = cvt_pk(hq[i * 4 + 2], hq[i * 4 + 3]);
      *(uint2*)&hsh[wave][kg * 4 + i][arow * 4] = make_uint2(p0, p1);
    }
  }
  float hq[16];
  STEP(TT - 1, false, hq);               // final h stays in registers

  // fused hj: hj[b][s][n] = sum_j h[j]*lw[s][j] + lb[s]; reduce over arow lanes
  #pragma unroll
  for (int i = 0; i < 4; i++) {
    float a[12];
    #pragma unroll
    for (int s = 0; s < 12; s++) a[s] = 0.f;
    #pragma unroll
    for (int njt = 0; njt < 4; njt++) {
      float hv = hq[i * 4 + njt];
      #pragma unroll
      for (int s = 0; s < 12; s++)
        a[s] = fmaf(hv, lwsh[s * 64 + arow * 4 + njt], a[s]);
    }
    #pragma unroll
    for (int off = 1; off < 16; off <<= 1) {
      #pragma unroll
      for (int s = 0; s < 12; s++) a[s] += __shfl_xor(a[s], off);
    }
    float outv = a[0];                   // static select chain (rule #20)
    #pragma unroll
    for (int s = 1; s < 12; s++) outv = (arow == s) ? a[s] : outv;
    if (arow < 12) {
      int gseq = seq_base + kg * 4 + i;
      int bb = gseq / 1000, nn = gseq - bb * 1000;
      hj[(size_t)(bb * 12 + arow) * NNODE + nn] = outv + lbsh[arow];
    }
  }
}

// ---------------- K_prep: layer-2 weights transposed into ws ----------------
// wt layout (all fp32): [0..767] lin_w^T [k][s]; [768..779] lin_b;
// [784..1935] mp1_w^T [c][o=32]; [1936..1967] mp1_b;
// [1968..5807] mp2_w^T [c][o=40]; [5808..5847] mp2_b.
__global__ void k_prep(const float* __restrict__ lw, const float* __restrict__ lb,
                       const float* __restrict__ w1, const float* __restrict__ b1,
                       const float* __restrict__ w2, const float* __restrict__ b2,
                       float* __restrict__ wt) {
  int tid = threadIdx.x;
  for (int i = tid; i < 768; i += 256) { int k = i / 12, s = i % 12; wt[i] = lw[s * 64 + k]; }
  if (tid < 12) wt[768 + tid] = lb[tid];
  for (int i = tid; i < 1152; i += 256) { int c = i / 32, o = i % 32; wt[784 + i] = w1[o * 36 + c]; }
  if (tid < 32) wt[1936 + tid] = b1[tid];
  for (int i = tid; i < 3840; i += 256) { int c = i / 40, o = i % 40; wt[1968 + i] = w2[o * 96 + c]; }
  if (tid < 40) wt[5808 + tid] = b2[tid];
}

// ---------------- K5/K7: mixprop propagation (gdep=2) -----------------------
__global__ void k_prop(const float* __restrict__ hin, const int2* __restrict__ pae,
                       float* __restrict__ ho, int C) {
  int blk = blockIdx.x;
  int b = blk / C, c = blk % C;
  __shared__ float r0[NNODE], r1[NNODE];
  int tid = threadIdx.x;
  const float* src = hin + (size_t)(b * C + c) * NNODE;
  float* dst = ho + (size_t)(b * 3 * C) * NNODE;
  for (int n = tid; n < NNODE; n += 256) {
    float vv = src[n]; r0[n] = vv; dst[(size_t)c * NNODE + n] = vv;
  }
  __syncthreads();
  for (int n = tid; n < NNODE; n += 256) {
    const int2* pa = pae + n * EPR;
    float s = 0.f;
    #pragma unroll
    for (int e = 0; e < EPR; e++) { int2 p = pa[e]; s = fmaf(__int_as_float(p.y), r0[p.x], s); }
    float h1 = 0.05f * r0[n] + 0.95f * s;
    r1[n] = h1; dst[(size_t)(C + c) * NNODE + n] = h1;
  }
  __syncthreads();
  for (int n = tid; n < NNODE; n += 256) {
    const int2* pa = pae + n * EPR;
    float s = 0.f;
    #pragma unroll
    for (int e = 0; e < EPR; e++) { int2 p = pa[e]; s = fmaf(__int_as_float(p.y), r1[p.x], s); }
    dst[(size_t)(2 * C + c) * NNODE + n] = 0.05f * r0[n] + 0.95f * s;
  }
}

// ---------------- K6/K8: channel projection (uniform weights -> SGPR) -------
template <int CIN, int COUT>
__global__ void k_proj(const float* __restrict__ hin, const float* __restrict__ wt,
                       const float* __restrict__ bb, float* __restrict__ out, int relu) {
  int id = blockIdx.x * 256 + threadIdx.x;   // (b,n)
  int b = id / NNODE, n = id % NNODE;
  float acc[COUT];
  #pragma unroll
  for (int o = 0; o < COUT; o++) acc[o] = bb[o];
  for (int c = 0; c < CIN; c++) {
    float hv = hin[(size_t)(b * CIN + c) * NNODE + n];
    #pragma unroll
    for (int o = 0; o < COUT; o++) acc[o] = fmaf(hv, wt[c * COUT + o], acc[o]);
  }
  #pragma unroll
  for (int o = 0; o < COUT; o++) {
    float vv = acc[o];
    if (relu) vv = fmaxf(vv, 0.f);
    out[(size_t)(b * COUT + o) * NNODE + n] = vv;
  }
}

// ---------------- K9: layernorm stats over (40,1000) per batch --------------
__global__ void k_lnstat(const float* __restrict__ hj2, float* __restrict__ stat) {
  int b = blockIdx.x, tid = threadIdx.x, lane = tid & 63, wave = tid >> 6;
  const float* p = hj2 + (size_t)b * DD * NNODE;
  float s = 0.f, q = 0.f;
  for (int i = tid; i < DD * NNODE; i += 256) { float vv = p[i]; s += vv; q = fmaf(vv, vv, q); }
  for (int off = 32; off; off >>= 1) { s += __shfl_down(s, off); q += __shfl_down(q, off); }
  __shared__ float ss[4], sq[4];
  if (lane == 0) { ss[wave] = s; sq[wave] = q; }
  __syncthreads();
  if (tid == 0) {
    const float invN = 1.0f / (float)(DD * NNODE);
    float S = ss[0] + ss[1] + ss[2] + ss[3];
    float Q = sq[0] + sq[1] + sq[2] + sq[3];
    float mu = S * invN;
    float var = Q * invN - mu * mu;
    stat[2 * b] = mu; stat[2 * b + 1] = __builtin_amdgcn_rsqf(var + 1e-5f);
  }
}

// ---------------- K10: apply LN + transpose + fp32 out ----------------------
__global__ void k_lnapply(const float* __restrict__ hj2, const float* __restrict__ stat,
                          const float* __restrict__ gamma, const float* __restrict__ beta,
                          float* __restrict__ out) {
  int id = blockIdx.x * 256 + threadIdx.x;   // (b,n)
  int b = id / NNODE, n = id % NNODE;
  float mu = stat[2 * b], rstd = stat[2 * b + 1];
  size_t obase = (size_t)b * (NNODE * DD) + (size_t)n * DD;
  #pragma unroll
  for (int d0 = 0; d0 < DD / 4; d0++) {
    float tt[4];
    #pragma unroll
    for (int q = 0; q < 4; q++) {
      int d = d0 * 4 + q;
      float h0 = hj2[(size_t)(b * DD + d) * NNODE + n];
      tt[q] = (h0 - mu) * rstd * gamma[d * NNODE + n] + beta[d * NNODE + n];
    }
    *(float4*)(out + obase + d0 * 4) = (float4){tt[0], tt[1], tt[2], tt[3]};
  }
}

// ---------------- workspace layout (fp32 words) -----------------------------
// 0        m1(40000) | 40000 m2(40000) | 80000 pae(21000 int2 = 42000 words)
// 122000   ho2(6.144M) [region reused]
// 4218000  hj(768000) | 4986000 ho1(2.304M) | 7290000 o1(2.048M)
// 9338000  hj2(2.56M) | 11898000 stat(128) | 11898128 wt(5848)   total ~47.6 MB
#define OFF_M1   0
#define OFF_M2   40000
#define OFF_PAE  80000
#define OFF_HJ   4218000
#define OFF_HO1  4986000
#define OFF_O1   7290000
#define OFF_HO2  122000
#define OFF_HJ2  9338000
#define OFF_STAT 11898000
#define OFF_WT   11898128

extern "C" void kernel_launch(void* const* d_in, const int* in_sizes, int n_in,
                              void* d_out, int out_size, void* d_ws, size_t ws_size,
                              hipStream_t stream) {
  (void)in_sizes; (void)n_in; (void)out_size; (void)ws_size;
  const float* x     = (const float*)d_in[0];
  const float* emb1  = (const float*)d_in[1];
  const float* emb2  = (const float*)d_in[2];
  const float* l1w   = (const float*)d_in[3];
  const float* l1b   = (const float*)d_in[4];
  const float* l2w   = (const float*)d_in[5];
  const float* l2b   = (const float*)d_in[6];
  const float* Wih   = (const float*)d_in[7];
  const float* Whh   = (const float*)d_in[8];
  const float* bih   = (const float*)d_in[9];
  const float* bhh   = (const float*)d_in[10];
  const float* lin_w = (const float*)d_in[11];
  const float* lin_b = (const float*)d_in[12];
  const float* mp1w  = (const float*)d_in[13];
  const float* mp1b  = (const float*)d_in[14];
  const float* mp2w  = (const float*)d_in[15];
  const float* mp2b  = (const float*)d_in[16];
  const float* gamma = (const float*)d_in[17];
  const float* beta  = (const float*)d_in[18];

  float* ws   = (float*)d_ws;
  float* m1   = ws + OFF_M1;
  float* m2   = ws + OFF_M2;
  int2*  pae  = (int2*)(ws + OFF_PAE);
  float* hj   = ws + OFF_HJ;
  float* ho1  = ws + OFF_HO1;
  float* o1   = ws + OFF_O1;
  float* ho2  = ws + OFF_HO2;
  float* hj2  = ws + OFF_HJ2;
  float* stat = ws + OFF_STAT;
  float* wt   = ws + OFF_WT;

  k_m1m2<<<dim3(313), dim3(256), 0, stream>>>(emb1, emb2, l1w, l1b, l2w, l2b, m1, m2);
  k_prep<<<dim3(1), dim3(256), 0, stream>>>(lin_w + 1536, lin_b + 24, mp1w + 2304, mp1b + 64,
                                            mp2w + 7680, mp2b + 80, wt);
  k_adj<<<dim3(NNODE), dim3(256), 0, stream>>>(m1, m2, pae);
  k_lstm<<<dim3(1000), dim3(256), 0, stream>>>(x, Wih, Whh, bih, bhh, wt, hj);
  k_prop<<<dim3(64 * 12), dim3(256), 0, stream>>>(hj, pae, ho1, 12);
  k_proj<36, 32><<<dim3(250), dim3(256), 0, stream>>>(ho1, wt + 784, wt + 1936, o1, 1);
  k_prop<<<dim3(64 * 32), dim3(256), 0, stream>>>(o1, pae, ho2, 32);
  k_proj<96, 40><<<dim3(250), dim3(256), 0, stream>>>(ho2, wt + 1968, wt + 5808, hj2, 0);
  k_lnstat<<<dim3(NB), dim3(256), 0, stream>>>(hj2, stat);
  k_lnapply<<<dim3(250), dim3(256), 0, stream>>>(hj2, stat, gamma + 80000, beta + 80000,
                                                 (float*)d_out);
}

// Round 12
// 262.165 us; speedup vs baseline: 1.8537x; 1.1723x over previous
//
#include <hip/hip_runtime.h>

// ---------------------------------------------------------------------------
// net_lstm: graph-constructor (topk-20 sparse adj) + per-node LSTM (bf16 MFMA)
//           + mixprop x2 (sparse gather + uniform-weight proj) + layernorm.
// Only layer j=2 of the 3 layers affects the output (reference overwrites h).
// ALL tensors are FLOAT32 on device. LSTM matmul in bf16 MFMA, rest fp32.
// k_lstm design notes (measured):
//  - REGISTER/ILP-bound: 16 independent accumulators (64 AGPR) + 48
//    back-to-back MFMAs per step beat a 16-AGPR low-ILP variant by 10%
//    (r8 95.8us vs r9 105.5us). Per-wave ILP is the lever, not wave count.
//  - __launch_bounds__ min-waves MUST stay 2: (256,4) caps regs at 128 incl
//    AGPRs -> 850 MB scratch spill, 2.5x slower (r7, measured).
//  - r10's raw asm("v_exp_f32") + weight pre-scaling produced zero output
//    (failed launch or miscompile) — keep __expf; no hand-rolled trans asm.
// r12: non-LSTM pass — float4 dots (k_adj/k_m1m2), int4-paired adjacency
// (EPR padded 21->22), 1024-thr float4 lnstat, prep merged into m1m2.
// ---------------------------------------------------------------------------

typedef unsigned short u16;
typedef __attribute__((ext_vector_type(8))) short bf16x8;   // 8 bf16 = 4 VGPR (MFMA A/B frag)
typedef __attribute__((ext_vector_type(4))) float fx4;      // MFMA C/D frag

#define NB 64          // batch
#define NNODE 1000
#define TT 12
#define FF 32
#define HH 64
#define DD 40
#define TOPK_ 20
#define EPR2 22        // adjacency entries per row: topk + diagonal + 1 pad (16B align)

__device__ __forceinline__ float rcp_f(float x) { return __builtin_amdgcn_rcpf(x); }
__device__ __forceinline__ float tanh_f(float x) {          // NaN-safe: e>=0 always
  return fmaf(-2.0f, rcp_f(__expf(2.0f * x) + 1.0f), 1.0f);
}
__device__ __forceinline__ unsigned int cvt_pk(float lo, float hi) {
  unsigned int r;                                           // r = [bf16(hi)|bf16(lo)]
  asm("v_cvt_pk_bf16_f32 %0, %1, %2" : "=v"(r) : "v"(lo), "v"(hi));
  return r;
}
__device__ __forceinline__ bf16x8 cvt8(const float* p) {    // 8 fp32 -> bf16x8 (4 cvt_pk)
  union { unsigned int u[4]; bf16x8 v; } r;
  #pragma unroll
  for (int e = 0; e < 4; e++) r.u[e] = cvt_pk(p[2 * e], p[2 * e + 1]);
  return r.v;
}
__device__ __forceinline__ bf16x8 cvt8v(float4 a, float4 b) {
  union { unsigned int u[4]; bf16x8 v; } r;
  r.u[0] = cvt_pk(a.x, a.y); r.u[1] = cvt_pk(a.z, a.w);
  r.u[2] = cvt_pk(b.x, b.y); r.u[3] = cvt_pk(b.z, b.w);
  return r.v;
}

// ---------------- K1: m1/m2 = tanh(3*(emb @ w^T + b)) + merged k_prep -------
// Block 313 (last) performs the weight transposition (wt layout below).
__global__ void k_m1m2(const float* __restrict__ emb1, const float* __restrict__ emb2,
                       const float* __restrict__ w1, const float* __restrict__ b1,
                       const float* __restrict__ w2, const float* __restrict__ b2,
                       float* __restrict__ m1, float* __restrict__ m2,
                       const float* __restrict__ lw, const float* __restrict__ lb,
                       const float* __restrict__ p1w, const float* __restrict__ p1b,
                       const float* __restrict__ p2w, const float* __restrict__ p2b,
                       float* __restrict__ wt) {
  int tid = threadIdx.x;
  if (blockIdx.x == 313) {               // merged k_prep
    for (int i = tid; i < 768; i += 256) { int k = i / 12, s = i % 12; wt[i] = lw[s * 64 + k]; }
    if (tid < 12) wt[768 + tid] = lb[tid];
    for (int i = tid; i < 1152; i += 256) { int c = i / 32, o = i % 32; wt[784 + i] = p1w[o * 36 + c]; }
    if (tid < 32) wt[1936 + tid] = p1b[tid];
    for (int i = tid; i < 3840; i += 256) { int c = i / 40, o = i % 40; wt[1968 + i] = p2w[o * 96 + c]; }
    if (tid < 40) wt[5808 + tid] = p2b[tid];
    return;
  }
  int id = blockIdx.x * 256 + tid;
  if (id >= 2 * NNODE * DD) return;
  int sel = id / (NNODE * DD);
  int r = id % (NNODE * DD);
  int i = r / DD, o = r % DD;
  const float4* emb = (const float4*)((sel ? emb2 : emb1) + i * DD);
  const float4* w = (const float4*)((sel ? w2 : w1) + o * DD);
  float s = (sel ? b2 : b1)[o];
  #pragma unroll
  for (int k4 = 0; k4 < DD / 4; k4++) {
    float4 a = emb[k4], b = w[k4];
    s = fmaf(a.x, b.x, s); s = fmaf(a.y, b.y, s);
    s = fmaf(a.z, b.z, s); s = fmaf(a.w, b.w, s);
  }
  (sel ? m2 : m1)[r] = tanh_f(3.0f * s);
}

// ---------------- K2: adjacency row + top-20 + normalize --------------------
// Scores via float4 dots. Selection: wave 0 only, scores in 16 regs/lane,
// 20 passes of __shfl_xor butterfly — zero barriers, static reg indices.
// Tie: value desc, idx asc. Output: EPR2=22 int2 entries (entry 21 = pad,
// val 0, contributes exactly nothing) so k_prop can load int4 pairs.
__global__ void k_adj(const float* __restrict__ m1, const float* __restrict__ m2,
                      int2* __restrict__ pae) {
  int v = blockIdx.x, tid = threadIdx.x;
  __shared__ float arow[NNODE];
  __shared__ float m1v[DD], m2v[DD];
  if (tid < DD) { m1v[tid] = m1[v * DD + tid]; m2v[tid] = m2[v * DD + tid]; }
  __syncthreads();
  for (int w = tid; w < NNODE; w += 256) {
    const float4* m2r = (const float4*)(m2 + w * DD);
    const float4* m1r = (const float4*)(m1 + w * DD);
    float d1 = 0.f, d2 = 0.f;
    #pragma unroll
    for (int k4 = 0; k4 < DD / 4; k4++) {
      float4 a = m2r[k4], b = m1r[k4];
      d1 = fmaf(m1v[k4 * 4 + 0], a.x, d1); d1 = fmaf(m1v[k4 * 4 + 1], a.y, d1);
      d1 = fmaf(m1v[k4 * 4 + 2], a.z, d1); d1 = fmaf(m1v[k4 * 4 + 3], a.w, d1);
      d2 = fmaf(m2v[k4 * 4 + 0], b.x, d2); d2 = fmaf(m2v[k4 * 4 + 1], b.y, d2);
      d2 = fmaf(m2v[k4 * 4 + 2], b.z, d2); d2 = fmaf(m2v[k4 * 4 + 3], b.w, d2);
    }
    arow[w] = fmaxf(tanh_f(3.0f * (d1 - d2)), 0.0f);
  }
  __syncthreads();
  if (tid >= 64) return;                 // selection: wave 0 only
  int l = tid;
  float rv[16];
  #pragma unroll
  for (int q = 0; q < 16; q++) {
    int idx = q * 64 + l;
    rv[q] = (idx < NNODE) ? arow[idx] : -2.f;
  }
  float rs = 1.f;                        // diagonal contributes 1
  float myv = 0.f; int myi = 0;          // lane l carries selected entry (l-1)
  #pragma unroll
  for (int sel = 0; sel < TOPK_; sel++) {
    float bv = rv[0]; int bi = l;
    #pragma unroll
    for (int q = 1; q < 16; q++) {
      int idx = q * 64 + l;
      if (rv[q] > bv) { bv = rv[q]; bi = idx; }   // ascending q => lowest idx on tie
    }
    #pragma unroll
    for (int off = 1; off < 64; off <<= 1) {
      float ov = __shfl_xor(bv, off); int oi = __shfl_xor(bi, off);
      if (ov > bv || (ov == bv && oi < bi)) { bv = ov; bi = oi; }
    }
    rs += bv;
    if (l == sel + 1) { myv = bv; myi = bi; }
    #pragma unroll
    for (int q = 0; q < 16; q++)
      if (q * 64 + l == bi) rv[q] = -2.f;         // invalidate winner
  }
  float inv = rcp_f(rs);
  if (l == 0)          pae[v * EPR2] = make_int2(v, __float_as_int(inv));
  else if (l <= TOPK_) pae[v * EPR2 + l] = make_int2(myi, __float_as_int(myv * inv));
  else if (l == 21)    pae[v * EPR2 + 21] = make_int2(v, 0);   // pad: val 0
}

// ---------------- K3: LSTM (12 steps, bf16 MFMA) + fused hj epilogue --------
// 4 waves/block; wave owns 16 seqs. Column remap: logical col L=nt*16+c holds
// gate g=nt>>2, hidden j=c*4+(nt&3) => thread(c=arow) owns (seq kg*4+i,
// j=arow*4+njt) with i/f/g/o in the same lane (tiles njt,njt+4,+8,+12).
// Full-ILP inner loop: 16 independent accumulators, 48 MFMAs back-to-back,
// gates once per step (r8 structure, fastest measured). hsh shuttle is
// WAVE-PRIVATE: DS ops in-order per wave => compiler fences only, no block
// barrier in the main loop. Epilogue: hj = h @ lin_w2^T + b with h still in
// registers (shfl_xor butterfly over the 16 arow lanes, static select chain).
__global__ __launch_bounds__(256, 2)
void k_lstm(const float* __restrict__ x, const float* __restrict__ Wih,
            const float* __restrict__ Whh, const float* __restrict__ bih,
            const float* __restrict__ bhh, const float* __restrict__ wt,
            float* __restrict__ hj) {
  __shared__ __align__(16) u16 whf[2 * 16 * 64 * 8];  // Whh frags (32 KB)
  __shared__ __align__(16) u16 hsh[4][16][64];        // per-wave h shuttle (8 KB)
  __shared__ float lwsh[12 * 64];                     // lin_w2 [s][j] (3 KB)
  __shared__ float lbsh[12];
  int tid = threadIdx.x, wave = tid >> 6, lane = tid & 63;
  int arow = lane & 15, kg = lane >> 4;

  // stage Whh frags: frag(ks,nt,l,e) = Whh[row=(nt>>2)*64+(l&15)*4+(nt&3)][ks*32+(l>>4)*8+e]
  for (int cc = tid; cc < 2 * 16 * 64; cc += 256) {
    int l = cc & 63, t16 = cc >> 6, ks = t16 >> 4, nt = t16 & 15;
    int row = (nt >> 2) * 64 + (l & 15) * 4 + (nt & 3);
    *(bf16x8*)&whf[cc * 8] = cvt8(Whh + row * 64 + ks * 32 + (l >> 4) * 8);
  }
  for (int i = tid; i < 768; i += 256) { int s = i >> 6, j = i & 63; lwsh[i] = wt[j * 12 + s]; }
  if (tid < 12) lbsh[tid] = wt[768 + tid];
  __syncthreads();                                    // the ONLY block barrier

  bf16x8 wi[16];                                      // Wih fragments in registers
  float biasv[16];
  #pragma unroll
  for (int nt = 0; nt < 16; nt++) {
    int row = (nt >> 2) * 64 + arow * 4 + (nt & 3);
    wi[nt] = cvt8(Wih + row * 32 + kg * 8);
    biasv[nt] = bih[row] + bhh[row];
  }

  int seq_base = blockIdx.x * 64 + wave * 16;
  const float* xb = x + (size_t)(seq_base + arow) * (TT * FF) + kg * 8;
  float cst[16];
  #pragma unroll
  for (int q = 0; q < 16; q++) cst[q] = 0.f;

  float4 xf0 = *(const float4*)(xb);                  // prefetch t=0
  float4 xf1 = *(const float4*)(xb + 4);

  auto STEP = [&](int t, bool first, float (&hq)[16]) {
    unsigned int zo = 0;                 // opaque zero: whf addrs loop-variant
    asm volatile("" : "+v"(zo));
    bf16x8 xa = cvt8v(xf0, xf1);
    if (t < TT - 1) {                    // prefetch x(t+1); hides under compute
      xf0 = *(const float4*)(xb + (t + 1) * FF);
      xf1 = *(const float4*)(xb + (t + 1) * FF + 4);
    }
    fx4 acc[16];
    #pragma unroll
    for (int nt = 0; nt < 16; nt++)
      acc[nt] = (fx4){biasv[nt], biasv[nt], biasv[nt], biasv[nt]};
    #pragma unroll
    for (int nt = 0; nt < 16; nt++)
      acc[nt] = __builtin_amdgcn_mfma_f32_16x16x32_bf16(xa, wi[nt], acc[nt], 0, 0, 0);
    if (!first) {
      asm volatile("" ::: "memory");     // reads stay after prev-step writes
      bf16x8 ha0 = *(const bf16x8*)&hsh[wave][arow][kg * 8];
      bf16x8 ha1 = *(const bf16x8*)&hsh[wave][arow][32 + kg * 8];
      asm volatile("" ::: "memory");     // this-step writes stay after reads
      #pragma unroll
      for (int nt = 0; nt < 16; nt++) {
        bf16x8 wb = *(const bf16x8*)&whf[(nt * 64 + lane) * 8 + zo];
        acc[nt] = __builtin_amdgcn_mfma_f32_16x16x32_bf16(ha0, wb, acc[nt], 0, 0, 0);
      }
      #pragma unroll
      for (int nt = 0; nt < 16; nt++) {
        bf16x8 wb = *(const bf16x8*)&whf[((16 + nt) * 64 + lane) * 8 + zo];
        acc[nt] = __builtin_amdgcn_mfma_f32_16x16x32_bf16(ha1, wb, acc[nt], 0, 0, 0);
      }
    }
    // gates for (seq=kg*4+i, j=arow*4+njt). Common-denominator forms:
    // c=(cp*B+(eg-1)*A)*rcp(A*B), A=1+e^-f, B=(1+e^-i)(e^2g+1);
    // h=(ec-1)*rcp((ec+1)(1+e^-o)), ec=e^2c      [7 trans ops/unit]
    #pragma unroll
    for (int i = 0; i < 4; i++) {
      #pragma unroll
      for (int njt = 0; njt < 4; njt++) {
        float iv = acc[njt][i], fv = acc[njt + 4][i];
        float gv = acc[njt + 8][i], ov = acc[njt + 12][i];
        float cpv = cst[i * 4 + njt];
        float ei = __expf(-iv), ef = __expf(-fv);
        float eg = __expf(2.0f * gv), eo = __expf(-ov);
        float A = 1.0f + ef;
        float B = (1.0f + ei) * (eg + 1.0f);
        float c = fmaf(cpv, B, (eg - 1.0f) * A) * rcp_f(A * B);
        cst[i * 4 + njt] = c;
        float ec = __expf(2.0f * c);
        hq[i * 4 + njt] = (ec - 1.0f) * rcp_f((ec + 1.0f) * (1.0f + eo));
      }
    }
  };

  #pragma unroll 1
  for (int t = 0; t < TT - 1; t++) {
    float hq[16];
    STEP(t, t == 0, hq);
    #pragma unroll
    for (int i = 0; i < 4; i++) {
      unsigned int p0 = cvt_pk(hq[i * 4 + 0], hq[i * 4 + 1]);
      unsigned int p1 = cvt_pk(hq[i * 4 + 2], hq[i * 4 + 3]);
      *(uint2*)&hsh[wave][kg * 4 + i][arow * 4] = make_uint2(p0, p1);
    }
  }
  float hq[16];
  STEP(TT - 1, false, hq);               // final h stays in registers

  // fused hj: hj[b][s][n] = sum_j h[j]*lw[s][j] + lb[s]; reduce over arow lanes
  #pragma unroll
  for (int i = 0; i < 4; i++) {
    float a[12];
    #pragma unroll
    for (int s = 0; s < 12; s++) a[s] = 0.f;
    #pragma unroll
    for (int njt = 0; njt < 4; njt++) {
      float hv = hq[i * 4 + njt];
      #pragma unroll
      for (int s = 0; s < 12; s++)
        a[s] = fmaf(hv, lwsh[s * 64 + arow * 4 + njt], a[s]);
    }
    #pragma unroll
    for (int off = 1; off < 16; off <<= 1) {
      #pragma unroll
      for (int s = 0; s < 12; s++) a[s] += __shfl_xor(a[s], off);
    }
    float outv = a[0];                   // static select chain (rule #20)
    #pragma unroll
    for (int s = 1; s < 12; s++) outv = (arow == s) ? a[s] : outv;
    if (arow < 12) {
      int gseq = seq_base + kg * 4 + i;
      int bb = gseq / 1000, nn = gseq - bb * 1000;
      hj[(size_t)(bb * 12 + arow) * NNODE + nn] = outv + lbsh[arow];
    }
  }
}

// ---------------- K5/K7: mixprop propagation (gdep=2) -----------------------
// Adjacency rows are 22 int2 entries (176 B, 16B-aligned) -> 11 int4 loads.
__global__ void k_prop(const float* __restrict__ hin, const int2* __restrict__ pae,
                       float* __restrict__ ho, int C) {
  int blk = blockIdx.x;
  int b = blk / C, c = blk % C;
  __shared__ float r0[NNODE], r1[NNODE];
  int tid = threadIdx.x;
  const float* src = hin + (size_t)(b * C + c) * NNODE;
  float* dst = ho + (size_t)(b * 3 * C) * NNODE;
  for (int n = tid; n < NNODE; n += 256) {
    float vv = src[n]; r0[n] = vv; dst[(size_t)c * NNODE + n] = vv;
  }
  __syncthreads();
  for (int n = tid; n < NNODE; n += 256) {
    const int4* pa4 = (const int4*)(pae + (size_t)n * EPR2);
    float s = 0.f;
    #pragma unroll
    for (int e = 0; e < EPR2 / 2; e++) {
      int4 p = pa4[e];
      s = fmaf(__int_as_float(p.y), r0[p.x], s);
      s = fmaf(__int_as_float(p.w), r0[p.z], s);
    }
    float h1 = 0.05f * r0[n] + 0.95f * s;
    r1[n] = h1; dst[(size_t)(C + c) * NNODE + n] = h1;
  }
  __syncthreads();
  for (int n = tid; n < NNODE; n += 256) {
    const int4* pa4 = (const int4*)(pae + (size_t)n * EPR2);
    float s = 0.f;
    #pragma unroll
    for (int e = 0; e < EPR2 / 2; e++) {
      int4 p = pa4[e];
      s = fmaf(__int_as_float(p.y), r1[p.x], s);
      s = fmaf(__int_as_float(p.w), r1[p.z], s);
    }
    dst[(size_t)(2 * C + c) * NNODE + n] = 0.05f * r0[n] + 0.95f * s;
  }
}

// ---------------- K6/K8: channel projection (uniform weights -> SGPR) -------
template <int CIN, int COUT>
__global__ void k_proj(const float* __restrict__ hin, const float* __restrict__ wt,
                       const float* __restrict__ bb, float* __restrict__ out, int relu) {
  int id = blockIdx.x * 256 + threadIdx.x;   // (b,n)
  int b = id / NNODE, n = id % NNODE;
  float acc[COUT];
  #pragma unroll
  for (int o = 0; o < COUT; o++) acc[o] = bb[o];
  for (int c = 0; c < CIN; c++) {
    float hv = hin[(size_t)(b * CIN + c) * NNODE + n];
    #pragma unroll
    for (int o = 0; o < COUT; o++) acc[o] = fmaf(hv, wt[c * COUT + o], acc[o]);
  }
  #pragma unroll
  for (int o = 0; o < COUT; o++) {
    float vv = acc[o];
    if (relu) vv = fmaxf(vv, 0.f);
    out[(size_t)(b * COUT + o) * NNODE + n] = vv;
  }
}

// ---------------- K9: layernorm stats over (40,1000) per batch --------------
// 1024 threads (16 waves) + float4 loads: 4x the in-flight loads of the old
// 256-thr scalar version (64 blocks = 1 wave/CU was latency-bound).
__global__ void k_lnstat(const float* __restrict__ hj2, float* __restrict__ stat) {
  int b = blockIdx.x, tid = threadIdx.x, lane = tid & 63, wave = tid >> 6;
  const float4* p = (const float4*)(hj2 + (size_t)b * DD * NNODE);
  float s = 0.f, q = 0.f;
  for (int i = tid; i < DD * NNODE / 4; i += 1024) {
    float4 vv = p[i];
    s += vv.x + vv.y + vv.z + vv.w;
    q = fmaf(vv.x, vv.x, q); q = fmaf(vv.y, vv.y, q);
    q = fmaf(vv.z, vv.z, q); q = fmaf(vv.w, vv.w, q);
  }
  for (int off = 32; off; off >>= 1) { s += __shfl_down(s, off); q += __shfl_down(q, off); }
  __shared__ float ss[16], sq[16];
  if (lane == 0) { ss[wave] = s; sq[wave] = q; }
  __syncthreads();
  if (tid == 0) {
    const float invN = 1.0f / (float)(DD * NNODE);
    float S = 0.f, Q = 0.f;
    for (int t = 0; t < 16; t++) { S += ss[t]; Q += sq[t]; }
    float mu = S * invN;
    float var = Q * invN - mu * mu;
    stat[2 * b] = mu; stat[2 * b + 1] = __builtin_amdgcn_rsqf(var + 1e-5f);
  }
}

// ---------------- K10: apply LN + transpose + fp32 out ----------------------
__global__ void k_lnapply(const float* __restrict__ hj2, const float* __restrict__ stat,
                          const float* __restrict__ gamma, const float* __restrict__ beta,
                          float* __restrict__ out) {
  int id = blockIdx.x * 256 + threadIdx.x;   // (b,n)
  int b = id / NNODE, n = id % NNODE;
  float mu = stat[2 * b], rstd = stat[2 * b + 1];
  size_t obase = (size_t)b * (NNODE * DD) + (size_t)n * DD;
  #pragma unroll
  for (int d0 = 0; d0 < DD / 4; d0++) {
    float tt[4];
    #pragma unroll
    for (int q = 0; q < 4; q++) {
      int d = d0 * 4 + q;
      float h0 = hj2[(size_t)(b * DD + d) * NNODE + n];
      tt[q] = (h0 - mu) * rstd * gamma[d * NNODE + n] + beta[d * NNODE + n];
    }
    *(float4*)(out + obase + d0 * 4) = (float4){tt[0], tt[1], tt[2], tt[3]};
  }
}

// ---------------- workspace layout (fp32 words) -----------------------------
// 0        m1(40000) | 40000 m2(40000) | 80000 pae(22000 int2 = 44000 words)
// 124000   ho2(6.144M) [overlaps dead hj/ho1; ends 6268000 < o1 at 7290000]
// 4218000  hj(768000) | 4986000 ho1(2.304M) | 7290000 o1(2.048M)
// 9338000  hj2(2.56M) | 11898000 stat(128) | 11898128 wt(5848)   total ~47.6 MB
#define OFF_M1   0
#define OFF_M2   40000
#define OFF_PAE  80000
#define OFF_HJ   4218000
#define OFF_HO1  4986000
#define OFF_O1   7290000
#define OFF_HO2  124000
#define OFF_HJ2  9338000
#define OFF_STAT 11898000
#define OFF_WT   11898128

extern "C" void kernel_launch(void* const* d_in, const int* in_sizes, int n_in,
                              void* d_out, int out_size, void* d_ws, size_t ws_size,
                              hipStream_t stream) {
  (void)in_sizes; (void)n_in; (void)out_size; (void)ws_size;
  const float* x     = (const float*)d_in[0];
  const float* emb1  = (const float*)d_in[1];
  const float* emb2  = (const float*)d_in[2];
  const float* l1w   = (const float*)d_in[3];
  const float* l1b   = (const float*)d_in[4];
  const float* l2w   = (const float*)d_in[5];
  const float* l2b   = (const float*)d_in[6];
  const float* Wih   = (const float*)d_in[7];
  const float* Whh   = (const float*)d_in[8];
  const float* bih   = (const float*)d_in[9];
  const float* bhh   = (const float*)d_in[10];
  const float* lin_w = (const float*)d_in[11];
  const float* lin_b = (const float*)d_in[12];
  const float* mp1w  = (const float*)d_in[13];
  const float* mp1b  = (const float*)d_in[14];
  const float* mp2w  = (const float*)d_in[15];
  const float* mp2b  = (const float*)d_in[16];
  const float* gamma = (const float*)d_in[17];
  const float* beta  = (const float*)d_in[18];

  float* ws   = (float*)d_ws;
  float* m1   = ws + OFF_M1;
  float* m2   = ws + OFF_M2;
  int2*  pae  = (int2*)(ws + OFF_PAE);
  float* hj   = ws + OFF_HJ;
  float* ho1  = ws + OFF_HO1;
  float* o1   = ws + OFF_O1;
  float* ho2  = ws + OFF_HO2;
  float* hj2  = ws + OFF_HJ2;
  float* stat = ws + OFF_STAT;
  float* wt   = ws + OFF_WT;

  k_m1m2<<<dim3(314), dim3(256), 0, stream>>>(emb1, emb2, l1w, l1b, l2w, l2b, m1, m2,
                                              lin_w + 1536, lin_b + 24, mp1w + 2304,
                                              mp1b + 64, mp2w + 7680, mp2b + 80, wt);
  k_adj<<<dim3(NNODE), dim3(256), 0, stream>>>(m1, m2, pae);
  k_lstm<<<dim3(1000), dim3(256), 0, stream>>>(x, Wih, Whh, bih, bhh, wt, hj);
  k_prop<<<dim3(64 * 12), dim3(256), 0, stream>>>(hj, pae, ho1, 12);
  k_proj<36, 32><<<dim3(250), dim3(256), 0, stream>>>(ho1, wt + 784, wt + 1936, o1, 1);
  k_prop<<<dim3(64 * 32), dim3(256), 0, stream>>>(o1, pae, ho2, 32);
  k_proj<96, 40><<<dim3(250), dim3(256), 0, stream>>>(ho2, wt + 1968, wt + 5808, hj2, 0);
  k_lnstat<<<dim3(NB), dim3(1024), 0, stream>>>(hj2, stat);
  k_lnapply<<<dim3(250), dim3(256), 0, stream>>>(hj2, stat, gamma + 80000, beta + 80000,
                                                 (float*)d_out);
}

// Round 13
// 249.924 us; speedup vs baseline: 1.9444x; 1.0490x over previous
//
#include <hip/hip_runtime.h>

// ---------------------------------------------------------------------------
// net_lstm: graph-constructor (topk-20 sparse adj) + per-node LSTM (bf16 MFMA)
//           + mixprop x2 (sparse gather + uniform-weight proj) + layernorm.
// Only layer j=2 of the 3 layers affects the output (reference overwrites h).
// ALL tensors are FLOAT32 on device. LSTM matmul in bf16 MFMA, rest fp32.
// k_lstm design notes (measured):
//  - REGISTER/ILP-bound: 16 independent accumulators (64 AGPR) + 48
//    back-to-back MFMAs per step beat a 16-AGPR low-ILP variant by 10%
//    (r8 95.8us vs r9 105.5us). Per-wave ILP is the lever, not wave count.
//  - __launch_bounds__ min-waves MUST stay 2: (256,4) caps regs at 128 incl
//    AGPRs -> 850 MB scratch spill, 2.5x slower (r7, measured).
//  - r10's raw asm("v_exp_f32") + weight pre-scaling produced zero output —
//    keep __expf; no hand-rolled trans asm.
// r13: k_prop4 (4 channels/block, b128 LDS gathers, LDS-gather instrs /4);
// k_adj 4 rows/block (L2 traffic /4, per-wave parallel selection); mixprop
// d=0 copy eliminated (proj reads depth-0 from prop input directly).
// ---------------------------------------------------------------------------

typedef unsigned short u16;
typedef __attribute__((ext_vector_type(8))) short bf16x8;   // 8 bf16 = 4 VGPR (MFMA A/B frag)
typedef __attribute__((ext_vector_type(4))) float fx4;      // MFMA C/D frag

#define NB 64          // batch
#define NNODE 1000
#define TT 12
#define FF 32
#define HH 64
#define DD 40
#define TOPK_ 20
#define EPR2 22        // adjacency entries per row: topk + diagonal + 1 pad (16B align)

__device__ __forceinline__ float rcp_f(float x) { return __builtin_amdgcn_rcpf(x); }
__device__ __forceinline__ float tanh_f(float x) {          // NaN-safe: e>=0 always
  return fmaf(-2.0f, rcp_f(__expf(2.0f * x) + 1.0f), 1.0f);
}
__device__ __forceinline__ unsigned int cvt_pk(float lo, float hi) {
  unsigned int r;                                           // r = [bf16(hi)|bf16(lo)]
  asm("v_cvt_pk_bf16_f32 %0, %1, %2" : "=v"(r) : "v"(lo), "v"(hi));
  return r;
}
__device__ __forceinline__ bf16x8 cvt8(const float* p) {    // 8 fp32 -> bf16x8 (4 cvt_pk)
  union { unsigned int u[4]; bf16x8 v; } r;
  #pragma unroll
  for (int e = 0; e < 4; e++) r.u[e] = cvt_pk(p[2 * e], p[2 * e + 1]);
  return r.v;
}
__device__ __forceinline__ bf16x8 cvt8v(float4 a, float4 b) {
  union { unsigned int u[4]; bf16x8 v; } r;
  r.u[0] = cvt_pk(a.x, a.y); r.u[1] = cvt_pk(a.z, a.w);
  r.u[2] = cvt_pk(b.x, b.y); r.u[3] = cvt_pk(b.z, b.w);
  return r.v;
}

// ---------------- K1: m1/m2 = tanh(3*(emb @ w^T + b)) + merged k_prep -------
__global__ void k_m1m2(const float* __restrict__ emb1, const float* __restrict__ emb2,
                       const float* __restrict__ w1, const float* __restrict__ b1,
                       const float* __restrict__ w2, const float* __restrict__ b2,
                       float* __restrict__ m1, float* __restrict__ m2,
                       const float* __restrict__ lw, const float* __restrict__ lb,
                       const float* __restrict__ p1w, const float* __restrict__ p1b,
                       const float* __restrict__ p2w, const float* __restrict__ p2b,
                       float* __restrict__ wt) {
  int tid = threadIdx.x;
  if (blockIdx.x == 313) {               // merged k_prep
    for (int i = tid; i < 768; i += 256) { int k = i / 12, s = i % 12; wt[i] = lw[s * 64 + k]; }
    if (tid < 12) wt[768 + tid] = lb[tid];
    for (int i = tid; i < 1152; i += 256) { int c = i / 32, o = i % 32; wt[784 + i] = p1w[o * 36 + c]; }
    if (tid < 32) wt[1936 + tid] = p1b[tid];
    for (int i = tid; i < 3840; i += 256) { int c = i / 40, o = i % 40; wt[1968 + i] = p2w[o * 96 + c]; }
    if (tid < 40) wt[5808 + tid] = p2b[tid];
    return;
  }
  int id = blockIdx.x * 256 + tid;
  if (id >= 2 * NNODE * DD) return;
  int sel = id / (NNODE * DD);
  int r = id % (NNODE * DD);
  int i = r / DD, o = r % DD;
  const float4* emb = (const float4*)((sel ? emb2 : emb1) + i * DD);
  const float4* w = (const float4*)((sel ? w2 : w1) + o * DD);
  float s = (sel ? b2 : b1)[o];
  #pragma unroll
  for (int k4 = 0; k4 < DD / 4; k4++) {
    float4 a = emb[k4], b = w[k4];
    s = fmaf(a.x, b.x, s); s = fmaf(a.y, b.y, s);
    s = fmaf(a.z, b.z, s); s = fmaf(a.w, b.w, s);
  }
  (sel ? m2 : m1)[r] = tanh_f(3.0f * s);
}

// ---------------- K2: adjacency, 4 rows per block ----------------------------
// Score phase: each thread loads one w-row (m1/m2, 20 float4 regs) ONCE and
// dots it against all 4 v-rows (from LDS) -> L2 traffic /4 vs 1-row blocks.
// Selection: wave r runs row v0+r's top-20 butterfly concurrently (was
// wave-0-only). Tie: value desc, idx asc. Output: EPR2=22 int2 entries,
// entry 21 = pad with val 0 (exact no-op) for int4-paired consumers.
__global__ void k_adj(const float* __restrict__ m1, const float* __restrict__ m2,
                      int2* __restrict__ pae) {
  int v0 = blockIdx.x * 4, tid = threadIdx.x;
  int lane = tid & 63, wave = tid >> 6;
  __shared__ float arow4[4][1024];                    // 16 KB
  __shared__ float m1v4[4][DD], m2v4[4][DD];
  for (int i = tid; i < 4 * DD; i += 256) {
    int r = i / DD, k = i % DD;
    m1v4[r][k] = m1[(v0 + r) * DD + k];
    m2v4[r][k] = m2[(v0 + r) * DD + k];
  }
  __syncthreads();
  for (int w = tid; w < NNODE; w += 256) {
    const float4* m2r = (const float4*)(m2 + w * DD);
    const float4* m1r = (const float4*)(m1 + w * DD);
    float4 a[10], bb[10];
    #pragma unroll
    for (int k4 = 0; k4 < 10; k4++) { a[k4] = m2r[k4]; bb[k4] = m1r[k4]; }
    #pragma unroll
    for (int r = 0; r < 4; r++) {
      float d1 = 0.f, d2 = 0.f;
      #pragma unroll
      for (int k4 = 0; k4 < 10; k4++) {
        d1 = fmaf(m1v4[r][k4 * 4 + 0], a[k4].x, d1);
        d1 = fmaf(m1v4[r][k4 * 4 + 1], a[k4].y, d1);
        d1 = fmaf(m1v4[r][k4 * 4 + 2], a[k4].z, d1);
        d1 = fmaf(m1v4[r][k4 * 4 + 3], a[k4].w, d1);
        d2 = fmaf(m2v4[r][k4 * 4 + 0], bb[k4].x, d2);
        d2 = fmaf(m2v4[r][k4 * 4 + 1], bb[k4].y, d2);
        d2 = fmaf(m2v4[r][k4 * 4 + 2], bb[k4].z, d2);
        d2 = fmaf(m2v4[r][k4 * 4 + 3], bb[k4].w, d2);
      }
      arow4[r][w] = fmaxf(tanh_f(3.0f * (d1 - d2)), 0.0f);
    }
  }
  __syncthreads();
  int v = v0 + wave, l = lane;           // wave r selects for row v0+r
  float rv[16];
  #pragma unroll
  for (int q = 0; q < 16; q++) {
    int idx = q * 64 + l;
    rv[q] = (idx < NNODE) ? arow4[wave][idx] : -2.f;
  }
  float rs = 1.f;                        // diagonal contributes 1
  float myv = 0.f; int myi = 0;          // lane l carries selected entry (l-1)
  #pragma unroll
  for (int sel = 0; sel < TOPK_; sel++) {
    float bv = rv[0]; int bi = l;
    #pragma unroll
    for (int q = 1; q < 16; q++) {
      int idx = q * 64 + l;
      if (rv[q] > bv) { bv = rv[q]; bi = idx; }   // ascending q => lowest idx on tie
    }
    #pragma unroll
    for (int off = 1; off < 64; off <<= 1) {
      float ov = __shfl_xor(bv, off); int oi = __shfl_xor(bi, off);
      if (ov > bv || (ov == bv && oi < bi)) { bv = ov; bi = oi; }
    }
    rs += bv;
    if (l == sel + 1) { myv = bv; myi = bi; }
    #pragma unroll
    for (int q = 0; q < 16; q++)
      if (q * 64 + l == bi) rv[q] = -2.f;         // invalidate winner
  }
  float inv = rcp_f(rs);
  if (l == 0)          pae[v * EPR2] = make_int2(v, __float_as_int(inv));
  else if (l <= TOPK_) pae[v * EPR2 + l] = make_int2(myi, __float_as_int(myv * inv));
  else if (l == 21)    pae[v * EPR2 + 21] = make_int2(v, 0);   // pad: val 0
}

// ---------------- K3: LSTM (12 steps, bf16 MFMA) + fused hj epilogue --------
// (frozen since r11 — see design notes at top)
__global__ __launch_bounds__(256, 2)
void k_lstm(const float* __restrict__ x, const float* __restrict__ Wih,
            const float* __restrict__ Whh, const float* __restrict__ bih,
            const float* __restrict__ bhh, const float* __restrict__ wt,
            float* __restrict__ hj) {
  __shared__ __align__(16) u16 whf[2 * 16 * 64 * 8];  // Whh frags (32 KB)
  __shared__ __align__(16) u16 hsh[4][16][64];        // per-wave h shuttle (8 KB)
  __shared__ float lwsh[12 * 64];                     // lin_w2 [s][j] (3 KB)
  __shared__ float lbsh[12];
  int tid = threadIdx.x, wave = tid >> 6, lane = tid & 63;
  int arow = lane & 15, kg = lane >> 4;

  for (int cc = tid; cc < 2 * 16 * 64; cc += 256) {
    int l = cc & 63, t16 = cc >> 6, ks = t16 >> 4, nt = t16 & 15;
    int row = (nt >> 2) * 64 + (l & 15) * 4 + (nt & 3);
    *(bf16x8*)&whf[cc * 8] = cvt8(Whh + row * 64 + ks * 32 + (l >> 4) * 8);
  }
  for (int i = tid; i < 768; i += 256) { int s = i >> 6, j = i & 63; lwsh[i] = wt[j * 12 + s]; }
  if (tid < 12) lbsh[tid] = wt[768 + tid];
  __syncthreads();                                    // the ONLY block barrier

  bf16x8 wi[16];
  float biasv[16];
  #pragma unroll
  for (int nt = 0; nt < 16; nt++) {
    int row = (nt >> 2) * 64 + arow * 4 + (nt & 3);
    wi[nt] = cvt8(Wih + row * 32 + kg * 8);
    biasv[nt] = bih[row] + bhh[row];
  }

  int seq_base = blockIdx.x * 64 + wave * 16;
  const float* xb = x + (size_t)(seq_base + arow) * (TT * FF) + kg * 8;
  float cst[16];
  #pragma unroll
  for (int q = 0; q < 16; q++) cst[q] = 0.f;

  float4 xf0 = *(const float4*)(xb);                  // prefetch t=0
  float4 xf1 = *(const float4*)(xb + 4);

  auto STEP = [&](int t, bool first, float (&hq)[16]) {
    unsigned int zo = 0;                 // opaque zero: whf addrs loop-variant
    asm volatile("" : "+v"(zo));
    bf16x8 xa = cvt8v(xf0, xf1);
    if (t < TT - 1) {
      xf0 = *(const float4*)(xb + (t + 1) * FF);
      xf1 = *(const float4*)(xb + (t + 1) * FF + 4);
    }
    fx4 acc[16];
    #pragma unroll
    for (int nt = 0; nt < 16; nt++)
      acc[nt] = (fx4){biasv[nt], biasv[nt], biasv[nt], biasv[nt]};
    #pragma unroll
    for (int nt = 0; nt < 16; nt++)
      acc[nt] = __builtin_amdgcn_mfma_f32_16x16x32_bf16(xa, wi[nt], acc[nt], 0, 0, 0);
    if (!first) {
      asm volatile("" ::: "memory");
      bf16x8 ha0 = *(const bf16x8*)&hsh[wave][arow][kg * 8];
      bf16x8 ha1 = *(const bf16x8*)&hsh[wave][arow][32 + kg * 8];
      asm volatile("" ::: "memory");
      #pragma unroll
      for (int nt = 0; nt < 16; nt++) {
        bf16x8 wb = *(const bf16x8*)&whf[(nt * 64 + lane) * 8 + zo];
        acc[nt] = __builtin_amdgcn_mfma_f32_16x16x32_bf16(ha0, wb, acc[nt], 0, 0, 0);
      }
      #pragma unroll
      for (int nt = 0; nt < 16; nt++) {
        bf16x8 wb = *(const bf16x8*)&whf[((16 + nt) * 64 + lane) * 8 + zo];
        acc[nt] = __builtin_amdgcn_mfma_f32_16x16x32_bf16(ha1, wb, acc[nt], 0, 0, 0);
      }
    }
    #pragma unroll
    for (int i = 0; i < 4; i++) {
      #pragma unroll
      for (int njt = 0; njt < 4; njt++) {
        float iv = acc[njt][i], fv = acc[njt + 4][i];
        float gv = acc[njt + 8][i], ov = acc[njt + 12][i];
        float cpv = cst[i * 4 + njt];
        float ei = __expf(-iv), ef = __expf(-fv);
        float eg = __expf(2.0f * gv), eo = __expf(-ov);
        float A = 1.0f + ef;
        float B = (1.0f + ei) * (eg + 1.0f);
        float c = fmaf(cpv, B, (eg - 1.0f) * A) * rcp_f(A * B);
        cst[i * 4 + njt] = c;
        float ec = __expf(2.0f * c);
        hq[i * 4 + njt] = (ec - 1.0f) * rcp_f((ec + 1.0f) * (1.0f + eo));
      }
    }
  };

  #pragma unroll 1
  for (int t = 0; t < TT - 1; t++) {
    float hq[16];
    STEP(t, t == 0, hq);
    #pragma unroll
    for (int i = 0; i < 4; i++) {
      unsigned int p0 = cvt_pk(hq[i * 4 + 0], hq[i * 4 + 1]);
      unsigned int p1 = cvt_pk(hq[i * 4 + 2], hq[i * 4 + 3]);
      *(uint2*)&hsh[wave][kg * 4 + i][arow * 4] = make_uint2(p0, p1);
    }
  }
  float hq[16];
  STEP(TT - 1, false, hq);

  #pragma unroll
  for (int i = 0; i < 4; i++) {
    float a[12];
    #pragma unroll
    for (int s = 0; s < 12; s++) a[s] = 0.f;
    #pragma unroll
    for (int njt = 0; njt < 4; njt++) {
      float hv = hq[i * 4 + njt];
      #pragma unroll
      for (int s = 0; s < 12; s++)
        a[s] = fmaf(hv, lwsh[s * 64 + arow * 4 + njt], a[s]);
    }
    #pragma unroll
    for (int off = 1; off < 16; off <<= 1) {
      #pragma unroll
      for (int s = 0; s < 12; s++) a[s] += __shfl_xor(a[s], off);
    }
    float outv = a[0];                   // static select chain (rule #20)
    #pragma unroll
    for (int s = 1; s < 12; s++) outv = (arow == s) ? a[s] : outv;
    if (arow < 12) {
      int gseq = seq_base + kg * 4 + i;
      int bb = gseq / 1000, nn = gseq - bb * 1000;
      hj[(size_t)(bb * 12 + arow) * NNODE + nn] = outv + lbsh[arow];
    }
  }
}

// ---------------- K5/K7: mixprop propagation, 4 channels per block ----------
// LDS node-major r0t[n][4] (16 B/row): one ds_read_b128 per neighbor serves
// 4 channels -> gather instructions /4 vs per-channel blocks. d=0 output is
// NOT written (it equals the input; k_proj reads depth-0 from src directly).
// ho layout: [b][2C][N] = d1 channels then d2 channels.
__global__ void k_prop4(const float* __restrict__ hin, const int2* __restrict__ pae,
                        float* __restrict__ ho, int C) {
  int NG = C >> 2;
  int b = blockIdx.x / NG, g = blockIdx.x % NG;
  int c0 = g * 4;
  __shared__ __align__(16) float r0t[NNODE][4];       // 16 KB
  __shared__ __align__(16) float r1t[NNODE][4];       // 16 KB
  int tid = threadIdx.x;
  const float* src = hin + ((size_t)b * C + c0) * NNODE;
  float* dst = ho + (size_t)b * 2 * C * NNODE;
  for (int n = tid; n < NNODE; n += 256) {
    float4 v;
    v.x = src[n];
    v.y = src[NNODE + n];
    v.z = src[2 * NNODE + n];
    v.w = src[3 * NNODE + n];
    *(float4*)&r0t[n][0] = v;                         // contiguous-n => linear
  }
  __syncthreads();
  for (int n = tid; n < NNODE; n += 256) {
    const int4* pa4 = (const int4*)(pae + (size_t)n * EPR2);
    float4 s = {0.f, 0.f, 0.f, 0.f};
    #pragma unroll
    for (int e = 0; e < EPR2 / 2; e++) {
      int4 p = pa4[e];
      float av = __int_as_float(p.y);
      float4 rv = *(const float4*)&r0t[p.x][0];
      s.x = fmaf(av, rv.x, s.x); s.y = fmaf(av, rv.y, s.y);
      s.z = fmaf(av, rv.z, s.z); s.w = fmaf(av, rv.w, s.w);
      float aw = __int_as_float(p.w);
      float4 rw = *(const float4*)&r0t[p.z][0];
      s.x = fmaf(aw, rw.x, s.x); s.y = fmaf(aw, rw.y, s.y);
      s.z = fmaf(aw, rw.z, s.z); s.w = fmaf(aw, rw.w, s.w);
    }
    float4 x0 = *(const float4*)&r0t[n][0];
    float4 h1;
    h1.x = fmaf(0.95f, s.x, 0.05f * x0.x);
    h1.y = fmaf(0.95f, s.y, 0.05f * x0.y);
    h1.z = fmaf(0.95f, s.z, 0.05f * x0.z);
    h1.w = fmaf(0.95f, s.w, 0.05f * x0.w);
    *(float4*)&r1t[n][0] = h1;
    dst[(size_t)(c0 + 0) * NNODE + n] = h1.x;
    dst[(size_t)(c0 + 1) * NNODE + n] = h1.y;
    dst[(size_t)(c0 + 2) * NNODE + n] = h1.z;
    dst[(size_t)(c0 + 3) * NNODE + n] = h1.w;
  }
  __syncthreads();
  for (int n = tid; n < NNODE; n += 256) {
    const int4* pa4 = (const int4*)(pae + (size_t)n * EPR2);
    float4 s = {0.f, 0.f, 0.f, 0.f};
    #pragma unroll
    for (int e = 0; e < EPR2 / 2; e++) {
      int4 p = pa4[e];
      float av = __int_as_float(p.y);
      float4 rv = *(const float4*)&r1t[p.x][0];
      s.x = fmaf(av, rv.x, s.x); s.y = fmaf(av, rv.y, s.y);
      s.z = fmaf(av, rv.z, s.z); s.w = fmaf(av, rv.w, s.w);
      float aw = __int_as_float(p.w);
      float4 rw = *(const float4*)&r1t[p.z][0];
      s.x = fmaf(aw, rw.x, s.x); s.y = fmaf(aw, rw.y, s.y);
      s.z = fmaf(aw, rw.z, s.z); s.w = fmaf(aw, rw.w, s.w);
    }
    float4 x0 = *(const float4*)&r0t[n][0];
    dst[(size_t)(C + c0 + 0) * NNODE + n] = fmaf(0.95f, s.x, 0.05f * x0.x);
    dst[(size_t)(C + c0 + 1) * NNODE + n] = fmaf(0.95f, s.y, 0.05f * x0.y);
    dst[(size_t)(C + c0 + 2) * NNODE + n] = fmaf(0.95f, s.z, 0.05f * x0.z);
    dst[(size_t)(C + c0 + 3) * NNODE + n] = fmaf(0.95f, s.w, 0.05f * x0.w);
  }
}

// ---------------- K6/K8: channel projection -----------------------------------
// Depth-0 channels come straight from src0 (the prop input); d1/d2 from ho.
template <int C1, int COUT>
__global__ void k_proj(const float* __restrict__ src0, const float* __restrict__ src12,
                       const float* __restrict__ wt, const float* __restrict__ bb,
                       float* __restrict__ out, int relu) {
  int id = blockIdx.x * 256 + threadIdx.x;   // (b,n)
  int b = id / NNODE, n = id % NNODE;
  float acc[COUT];
  #pragma unroll
  for (int o = 0; o < COUT; o++) acc[o] = bb[o];
  for (int c = 0; c < C1; c++) {
    float hv = src0[(size_t)(b * C1 + c) * NNODE + n];
    #pragma unroll
    for (int o = 0; o < COUT; o++) acc[o] = fmaf(hv, wt[c * COUT + o], acc[o]);
  }
  for (int c = 0; c < 2 * C1; c++) {
    float hv = src12[(size_t)(b * 2 * C1 + c) * NNODE + n];
    #pragma unroll
    for (int o = 0; o < COUT; o++) acc[o] = fmaf(hv, wt[(C1 + c) * COUT + o], acc[o]);
  }
  #pragma unroll
  for (int o = 0; o < COUT; o++) {
    float vv = acc[o];
    if (relu) vv = fmaxf(vv, 0.f);
    out[(size_t)(b * COUT + o) * NNODE + n] = vv;
  }
}

// ---------------- K9: layernorm stats over (40,1000) per batch --------------
__global__ void k_lnstat(const float* __restrict__ hj2, float* __restrict__ stat) {
  int b = blockIdx.x, tid = threadIdx.x, lane = tid & 63, wave = tid >> 6;
  const float4* p = (const float4*)(hj2 + (size_t)b * DD * NNODE);
  float s = 0.f, q = 0.f;
  for (int i = tid; i < DD * NNODE / 4; i += 1024) {
    float4 vv = p[i];
    s += vv.x + vv.y + vv.z + vv.w;
    q = fmaf(vv.x, vv.x, q); q = fmaf(vv.y, vv.y, q);
    q = fmaf(vv.z, vv.z, q); q = fmaf(vv.w, vv.w, q);
  }
  for (int off = 32; off; off >>= 1) { s += __shfl_down(s, off); q += __shfl_down(q, off); }
  __shared__ float ss[16], sq[16];
  if (lane == 0) { ss[wave] = s; sq[wave] = q; }
  __syncthreads();
  if (tid == 0) {
    const float invN = 1.0f / (float)(DD * NNODE);
    float S = 0.f, Q = 0.f;
    for (int t = 0; t < 16; t++) { S += ss[t]; Q += sq[t]; }
    float mu = S * invN;
    float var = Q * invN - mu * mu;
    stat[2 * b] = mu; stat[2 * b + 1] = __builtin_amdgcn_rsqf(var + 1e-5f);
  }
}

// ---------------- K10: apply LN + transpose + fp32 out ----------------------
__global__ void k_lnapply(const float* __restrict__ hj2, const float* __restrict__ stat,
                          const float* __restrict__ gamma, const float* __restrict__ beta,
                          float* __restrict__ out) {
  int id = blockIdx.x * 256 + threadIdx.x;   // (b,n)
  int b = id / NNODE, n = id % NNODE;
  float mu = stat[2 * b], rstd = stat[2 * b + 1];
  size_t obase = (size_t)b * (NNODE * DD) + (size_t)n * DD;
  #pragma unroll
  for (int d0 = 0; d0 < DD / 4; d0++) {
    float tt[4];
    #pragma unroll
    for (int q = 0; q < 4; q++) {
      int d = d0 * 4 + q;
      float h0 = hj2[(size_t)(b * DD + d) * NNODE + n];
      tt[q] = (h0 - mu) * rstd * gamma[d * NNODE + n] + beta[d * NNODE + n];
    }
    *(float4*)(out + obase + d0 * 4) = (float4){tt[0], tt[1], tt[2], tt[3]};
  }
}

// ---------------- workspace layout (fp32 words, flat) ------------------------
// m1 40k | m2 40k | pae 44k | hj 768k | ho1 [64][24][1000]=1.536M |
// o1 2.048M | ho2 [64][64][1000]=4.096M | hj2 2.56M | stat 128 | wt 5848
#define OFF_M1   0
#define OFF_M2   40000
#define OFF_PAE  80000
#define OFF_HJ   124000
#define OFF_HO1  892000
#define OFF_O1   2428000
#define OFF_HO2  4476000
#define OFF_HJ2  8572000
#define OFF_STAT 11132000
#define OFF_WT   11132128

extern "C" void kernel_launch(void* const* d_in, const int* in_sizes, int n_in,
                              void* d_out, int out_size, void* d_ws, size_t ws_size,
                              hipStream_t stream) {
  (void)in_sizes; (void)n_in; (void)out_size; (void)ws_size;
  const float* x     = (const float*)d_in[0];
  const float* emb1  = (const float*)d_in[1];
  const float* emb2  = (const float*)d_in[2];
  const float* l1w   = (const float*)d_in[3];
  const float* l1b   = (const float*)d_in[4];
  const float* l2w   = (const float*)d_in[5];
  const float* l2b   = (const float*)d_in[6];
  const float* Wih   = (const float*)d_in[7];
  const float* Whh   = (const float*)d_in[8];
  const float* bih   = (const float*)d_in[9];
  const float* bhh   = (const float*)d_in[10];
  const float* lin_w = (const float*)d_in[11];
  const float* lin_b = (const float*)d_in[12];
  const float* mp1w  = (const float*)d_in[13];
  const float* mp1b  = (const float*)d_in[14];
  const float* mp2w  = (const float*)d_in[15];
  const float* mp2b  = (const float*)d_in[16];
  const float* gamma = (const float*)d_in[17];
  const float* beta  = (const float*)d_in[18];

  float* ws   = (float*)d_ws;
  float* m1   = ws + OFF_M1;
  float* m2   = ws + OFF_M2;
  int2*  pae  = (int2*)(ws + OFF_PAE);
  float* hj   = ws + OFF_HJ;
  float* ho1  = ws + OFF_HO1;
  float* o1   = ws + OFF_O1;
  float* ho2  = ws + OFF_HO2;
  float* hj2  = ws + OFF_HJ2;
  float* stat = ws + OFF_STAT;
  float* wt   = ws + OFF_WT;

  k_m1m2<<<dim3(314), dim3(256), 0, stream>>>(emb1, emb2, l1w, l1b, l2w, l2b, m1, m2,
                                              lin_w + 1536, lin_b + 24, mp1w + 2304,
                                              mp1b + 64, mp2w + 7680, mp2b + 80, wt);
  k_adj<<<dim3(250), dim3(256), 0, stream>>>(m1, m2, pae);
  k_lstm<<<dim3(1000), dim3(256), 0, stream>>>(x, Wih, Whh, bih, bhh, wt, hj);
  k_prop4<<<dim3(64 * 3), dim3(256), 0, stream>>>(hj, pae, ho1, 12);
  k_proj<12, 32><<<dim3(250), dim3(256), 0, stream>>>(hj, ho1, wt + 784, wt + 1936, o1, 1);
  k_prop4<<<dim3(64 * 8), dim3(256), 0, stream>>>(o1, pae, ho2, 32);
  k_proj<32, 40><<<dim3(250), dim3(256), 0, stream>>>(o1, ho2, wt + 1968, wt + 5808, hj2, 0);
  k_lnstat<<<dim3(NB), dim3(1024), 0, stream>>>(hj2, stat);
  k_lnapply<<<dim3(250), dim3(256), 0, stream>>>(hj2, stat, gamma + 80000, beta + 80000,
                                                 (float*)d_out);
}